// Round 7
// baseline (680.488 us; speedup 1.0000x reference)
//
#include <hip/hip_runtime.h>
#include <cstdint>
#include <cstddef>

typedef __attribute__((ext_vector_type(8))) short short8;   // 8 bf16 (4 VGPRs)
typedef __attribute__((ext_vector_type(4))) float f32x4;    // 4 fp32 acc
typedef __attribute__((ext_vector_type(4))) float f4;
typedef __attribute__((ext_vector_type(2))) float f2;
typedef __attribute__((ext_vector_type(4))) unsigned short us4;

#define NN 4096
#define HH 512
#define EE 65536
#define NBLK 256          // mega-kernel grid: <= #CUs -> all blocks co-resident

// async global->LDS, 16B per lane (dest must be linear: base + lane*16)
#define GLOAD(gp, lp) __builtin_amdgcn_global_load_lds( \
    (const __attribute__((address_space(1))) void*)(gp), \
    (__attribute__((address_space(3))) void*)(lp), 16, 0, 0)

__device__ __forceinline__ unsigned short f2bf(float x) {
    union { float f; unsigned u; } un; un.f = x;
    unsigned r = un.u + 0x7fffu + ((un.u >> 16) & 1u);   // round-to-nearest-even
    return (unsigned short)(r >> 16);
}
__device__ __forceinline__ float b2f(unsigned short v) {
    union { unsigned u; float f; } un; un.u = ((unsigned)v) << 16; return un.f;
}

// ---------------- device-wide barrier (all NBLK blocks co-resident) ----------------
__device__ __forceinline__ void gbar(int* cnt, int target) {
    __syncthreads();                     // all block writes issued (waitcnt before s_barrier)
    if (threadIdx.x == 0) {
        __threadfence();                 // agent-scope release (L2 writeback on gfx950)
        __hip_atomic_fetch_add(cnt, 1, __ATOMIC_RELEASE, __HIP_MEMORY_SCOPE_AGENT);
        while (__hip_atomic_load(cnt, __ATOMIC_ACQUIRE, __HIP_MEMORY_SCOPE_AGENT) < target)
            __builtin_amdgcn_s_sleep(1);
        __threadfence();                 // agent-scope acquire (L1/L2 invalidate)
    }
    __syncthreads();
}

// ---------------- edge sort: fused hist+scan (1 block), scatter, binsort ----------------
__global__ __launch_bounds__(1024) void k_histscan(const int* __restrict__ edst,
                                                   int* __restrict__ starts) {
    __shared__ int cnt[NN];
    __shared__ int wtot[16], woff[16];
    const int t = threadIdx.x;
    for (int i = t; i < NN; i += 1024) cnt[i] = 0;
    __syncthreads();
    for (int i = t; i < EE; i += 1024) atomicAdd(&cnt[edst[i]], 1);
    __syncthreads();
    const int b = t * 4;
    const int c0 = cnt[b], c1 = cnt[b + 1], c2 = cnt[b + 2], c3 = cnt[b + 3];
    const int s = c0 + c1 + c2 + c3;
    const int lane = t & 63, wv = t >> 6;
    int inc = s;
    for (int d = 1; d < 64; d <<= 1) {
        int v = __shfl_up(inc, d);
        if (lane >= d) inc += v;
    }
    if (lane == 63) wtot[wv] = inc;
    __syncthreads();
    if (t == 0) {
        int a = 0;
        for (int i = 0; i < 16; ++i) { woff[i] = a; a += wtot[i]; }
        starts[NN] = a;
    }
    __syncthreads();
    int run = woff[wv] + inc - s;
    starts[b] = run; run += c0;
    starts[b + 1] = run; run += c1;
    starts[b + 2] = run; run += c2;
    starts[b + 3] = run;
}

__global__ void k_scatter(const int* __restrict__ src, const int* __restrict__ dst,
                          const int* __restrict__ starts, int* __restrict__ cursor,
                          int* __restrict__ sorted) {
    int e = blockIdx.x * 256 + threadIdx.x;
    if (e < EE) {
        int d = dst[e];
        int p = starts[d] + atomicAdd(&cursor[d], 1);
        sorted[p] = src[e];
    }
}

__global__ void k_binsort(const int* __restrict__ starts, int* __restrict__ a) {
    int d = blockIdx.x * 256 + threadIdx.x;
    if (d < NN) {
        int s = starts[d], e = starts[d + 1];
        for (int i = s + 1; i < e; ++i) {
            int v = a[i]; int j = i - 1;
            while (j >= s && a[j] > v) { a[j + 1] = a[j]; --j; }
            a[j + 1] = v;
        }
    }
}

// ---------------- prep: blocks 0..4095 = cvt+dot0 slice; 4096.. = weight transposes ----------------
__global__ __launch_bounds__(256) void k_prep(const float* __restrict__ feat,
                                              const float* __restrict__ Wp0,
                                              unsigned short* __restrict__ featb,
                                              float* __restrict__ part,
                                              const float* __restrict__ W0a,
                                              const float* __restrict__ W0b,
                                              const float* __restrict__ WRa,
                                              const float* __restrict__ WRb,
                                              unsigned short* __restrict__ w0at,
                                              unsigned short* __restrict__ wt) {
    __shared__ f4 fs[1024];
    __shared__ float s0[256], s1[256];
    __shared__ float tile[32][33];
    const int t = threadIdx.x;
    const int bid = blockIdx.x;
    if (bid < 4096) {
        // ---- cvt + feat.Wp0 partial dot: block owns 1024 consecutive float4s ----
        const long B0 = (long)bid * 1024;
        const f4* ff = (const f4*)feat;
        const f4* ww = (const f4*)Wp0;
        f4 v[4];
#pragma unroll
        for (int k = 0; k < 4; ++k)
            v[k] = __builtin_nontemporal_load(ff + B0 + k * 256 + t);
#pragma unroll
        for (int k = 0; k < 4; ++k) {
            fs[k * 256 + t] = v[k];
            us4 o;
            o.x = f2bf(v[k].x); o.y = f2bf(v[k].y); o.z = f2bf(v[k].z); o.w = f2bf(v[k].w);
            __builtin_nontemporal_store(o, (us4*)featb + B0 + k * 256 + t);
        }
        f4 wv[8];
#pragma unroll
        for (int k = 0; k < 8; ++k)
            wv[k] = __builtin_nontemporal_load(ww + 2 * B0 + k * 256 + t);
        __syncthreads();
        float a0 = 0.f, a1 = 0.f;
#pragma unroll
        for (int k = 0; k < 8; ++k) {
            const int q = k * 256 + t;
            f2 fp = *(const f2*)((const char*)fs + (size_t)q * 8);
            a0 += fp.x * wv[k].x + fp.y * wv[k].z;
            a1 += fp.x * wv[k].y + fp.y * wv[k].w;
        }
        s0[t] = a0; s1[t] = a1;
        __syncthreads();
        for (int s = 128; s > 0; s >>= 1) {
            if (t < s) { s0[t] += s0[t + s]; s1[t] += s1[t + s]; }
            __syncthreads();
        }
        if (t == 0) { part[2 * bid] = s0[0]; part[2 * bid + 1] = s1[0]; }
    } else {
        // ---- weight transpose/convert tiles ----
        const int tix = bid - 4096;
        const float* W; unsigned short* Wt; int K, kb, nb;
        if (tix < 2048) {                 // W0a: 128 x 16 tiles of 32x32
            W = W0a; Wt = w0at; K = NN; kb = tix >> 4; nb = tix & 15;
        } else {
            const int t2 = tix - 2048;    // 7 x 256 tiles
            const int z = t2 >> 8, r = t2 & 255;
            W = (z == 0) ? W0b : (z < 4) ? WRa + (size_t)(z - 1) * HH * HH
                                         : WRb + (size_t)(z - 4) * HH * HH;
            Wt = wt + (size_t)z * HH * HH; K = HH; kb = r >> 4; nb = r & 15;
        }
        const int k0 = kb * 32, n0 = nb * 32;
        const int tx = t & 31, ty = t >> 5;
        for (int r = ty; r < 32; r += 8)
            tile[r][tx] = W[(size_t)(k0 + r) * HH + n0 + tx];
        __syncthreads();
        for (int r = ty; r < 32; r += 8)
            Wt[(size_t)(n0 + r) * K + k0 + tx] = f2bf(tile[tx][r]);
    }
}

// ================= mega kernel: all GEMM/agg layers + final, 256 blocks x 512 thr =================
struct MegaArgs {
    const unsigned short *featb, *w0at, *wt;
    unsigned short *G0b, *xb, *yb, *hb;
    const int *starts, *sorted;
    const float *eps0, *b0a, *bn0a_g, *bn0a_b, *bn0a_m, *bn0a_v;
    const float *b0b, *bnA0_g, *bnA0_b, *bnA0_m, *bnA0_v;
    const float *bnO0_g, *bnO0_b, *bnO0_m, *bnO0_v;
    const float *epsR, *bRa, *bnRa_g, *bnRa_b, *bnRa_m, *bnRa_v;
    const float *bRb, *bnAR_g, *bnAR_b, *bnAR_m, *bnAR_v;
    const float *bnOR_g, *bnOR_b, *bnOR_m, *bnOR_v;
    const float *WpR, *bp0, *bpR;
    float *part, *out;
    int *bar;
};

// GEMM phase: C = A[M=4096][K] @ Bt[512][K]^T, tile 128x64, BK=64, 8 waves.
// EPI 0: raw bf16. EPI 1: +bias,BN,ReLU -> bf16. EPI 3: +bias,BN,ReLU,BN,ReLU -> bf16 (+DOT).
template<int EPI, bool DOT>
__device__ __forceinline__ void gemm_phase(
    const unsigned short* __restrict__ A, const unsigned short* __restrict__ Bt, int K,
    const float* __restrict__ bias,
    const float* __restrict__ g1, const float* __restrict__ b1,
    const float* __restrict__ m1, const float* __restrict__ v1,
    const float* __restrict__ g2, const float* __restrict__ b2,
    const float* __restrict__ m2, const float* __restrict__ v2,
    unsigned short* __restrict__ outb,
    const float* __restrict__ wq, float* __restrict__ part, int slot,
    unsigned short* As, unsigned short* Bs)
{
    constexpr int N = HH;
    const int t = threadIdx.x;
    const int lane = t & 63, w = t >> 6;
    const int wr = w >> 1, wc = w & 1;               // 4 row-waves x 2 col-waves
    const int l15 = lane & 15, l4 = lane >> 4;
    const int m0 = (blockIdx.x >> 3) * 128, n0 = (blockIdx.x & 7) * 64;

    f32x4 acc[2][2];
#pragma unroll
    for (int i = 0; i < 2; ++i)
#pragma unroll
        for (int j = 0; j < 2; ++j) acc[i][j] = (f32x4){0.f, 0.f, 0.f, 0.f};

    // A tile 128x64 = 1024 16B chunks (2/thread); B tile 64x64 = 512 chunks (1/thread)
    const unsigned short* ga0 = A + (size_t)(m0 + (t >> 3)) * K + (t & 7) * 8;
    const unsigned short* ga1 = ga0 + (size_t)64 * K;
    const unsigned short* gb  = Bt + (size_t)(n0 + (t >> 3)) * K + (t & 7) * 8;

    auto stage = [&](int kt, int buf) {
        const int ko = kt * 64;
        GLOAD(ga0 + ko, As + buf * 8192 + t * 8);
        GLOAD(ga1 + ko, As + buf * 8192 + 4096 + t * 8);
        GLOAD(gb + ko,  Bs + buf * 4096 + t * 8);
    };

    const int nk = K >> 6;
    stage(0, 0);
    __syncthreads();
    for (int kt = 0; kt < nk; ++kt) {
        const int cur = kt & 1;
        if (kt + 1 < nk) stage(kt + 1, cur ^ 1);
        const unsigned short* Ac = As + cur * 8192;
        const unsigned short* Bc = Bs + cur * 4096;
        short8 aF[2][2], bF[2][2];
#pragma unroll
        for (int i = 0; i < 2; ++i)
#pragma unroll
            for (int ks = 0; ks < 2; ++ks)
                aF[i][ks] = *(const short8*)(Ac + (wr * 32 + i * 16 + l15) * 64 + ks * 32 + l4 * 8);
#pragma unroll
        for (int j = 0; j < 2; ++j)
#pragma unroll
            for (int ks = 0; ks < 2; ++ks)
                bF[j][ks] = *(const short8*)(Bc + (wc * 32 + j * 16 + l15) * 64 + ks * 32 + l4 * 8);
#pragma unroll
        for (int ks = 0; ks < 2; ++ks)
#pragma unroll
            for (int i = 0; i < 2; ++i)
#pragma unroll
                for (int j = 0; j < 2; ++j)
                    acc[i][j] = __builtin_amdgcn_mfma_f32_16x16x32_bf16(aF[i][ks], bF[j][ks], acc[i][j], 0, 0, 0);
        __syncthreads();
    }

    const int mrow = m0 + wr * 32;
    float d0 = 0.f, d1 = 0.f;
#pragma unroll
    for (int j = 0; j < 2; ++j) {
        const int cg = n0 + wc * 32 + j * 16 + l15;
        float bi = 0.f, sc1 = 1.f, sh1 = 0.f, sc2 = 1.f, sh2 = 0.f;
        if (EPI >= 1) {
            bi = bias[cg];
            sc1 = rsqrtf(v1[cg] + 1e-5f) * g1[cg];
            sh1 = b1[cg] - m1[cg] * sc1;
        }
        if (EPI == 3) {
            sc2 = rsqrtf(v2[cg] + 1e-5f) * g2[cg];
            sh2 = b2[cg] - m2[cg] * sc2;
        }
#pragma unroll
        for (int i = 0; i < 2; ++i) {
#pragma unroll
            for (int r = 0; r < 4; ++r) {
                const int rg = mrow + i * 16 + l4 * 4 + r;
                float x = acc[i][j][r];
                if (EPI >= 1) {
                    x = fmaxf((x + bi) * sc1 + sh1, 0.f);
                    if (EPI == 3) x = fmaxf(x * sc2 + sh2, 0.f);
                }
                outb[(size_t)rg * N + cg] = f2bf(x);
                if constexpr (DOT) {
                    f2 wvv = __builtin_nontemporal_load((const f2*)wq + (size_t)rg * N + cg);
                    d0 += x * wvv.x; d1 += x * wvv.y;
                }
            }
        }
    }
    if constexpr (DOT) {
        float* r0 = (float*)As;          // LDS scratch (frag reads all done)
        float* r1 = r0 + 512;
        __syncthreads();
        r0[t] = d0; r1[t] = d1;
        __syncthreads();
        for (int s = 256; s > 0; s >>= 1) {
            if (t < s) { r0[t] += r0[t + s]; r1[t] += r1[t + s]; }
            __syncthreads();
        }
        if (t == 0) { part[2 * slot] = r0[0]; part[2 * slot + 1] = r1[0]; }
    }
}

// agg phase: 16 dst rows per block (4 groups of 128 threads x 4 reps)
template<bool L0>
__device__ __forceinline__ void agg_phase(
    const unsigned short* __restrict__ src, unsigned short* __restrict__ dst,
    const int* __restrict__ starts, const int* __restrict__ sorted, float ep,
    const float* __restrict__ bias,
    const float* __restrict__ bg, const float* __restrict__ bb,
    const float* __restrict__ bm, const float* __restrict__ bv)
{
    const int t = threadIdx.x;
    const int tl = t & 127;
#pragma unroll
    for (int rep = 0; rep < 4; ++rep) {
        const int d = blockIdx.x * 16 + rep * 4 + (t >> 7);
        ushort4 ow = ((const ushort4*)(src + (size_t)d * HH))[tl];
        float sx = 0.f, sy = 0.f, sz = 0.f, sw = 0.f;
        const int e0 = starts[d], e1 = starts[d + 1];
        int i = e0;
        for (; i + 4 <= e1; i += 4) {
            int q0 = sorted[i], q1 = sorted[i + 1], q2 = sorted[i + 2], q3 = sorted[i + 3];
            ushort4 x0 = ((const ushort4*)(src + (size_t)q0 * HH))[tl];
            ushort4 x1 = ((const ushort4*)(src + (size_t)q1 * HH))[tl];
            ushort4 x2 = ((const ushort4*)(src + (size_t)q2 * HH))[tl];
            ushort4 x3 = ((const ushort4*)(src + (size_t)q3 * HH))[tl];
            sx += (b2f(x0.x) + b2f(x1.x)) + (b2f(x2.x) + b2f(x3.x));
            sy += (b2f(x0.y) + b2f(x1.y)) + (b2f(x2.y) + b2f(x3.y));
            sz += (b2f(x0.z) + b2f(x1.z)) + (b2f(x2.z) + b2f(x3.z));
            sw += (b2f(x0.w) + b2f(x1.w)) + (b2f(x2.w) + b2f(x3.w));
        }
        for (; i < e1; ++i) {
            ushort4 x = ((const ushort4*)(src + (size_t)sorted[i] * HH))[tl];
            sx += b2f(x.x); sy += b2f(x.y); sz += b2f(x.z); sw += b2f(x.w);
        }
        float x0 = ep * b2f(ow.x) + sx;
        float x1 = ep * b2f(ow.y) + sy;
        float x2 = ep * b2f(ow.z) + sz;
        float x3 = ep * b2f(ow.w) + sw;
        if constexpr (L0) {
            float4 bi = ((const float4*)bias)[tl];
            float4 g4 = ((const float4*)bg)[tl];
            float4 b4 = ((const float4*)bb)[tl];
            float4 m4 = ((const float4*)bm)[tl];
            float4 v4 = ((const float4*)bv)[tl];
            x0 = fmaxf((x0 + bi.x - m4.x) * rsqrtf(v4.x + 1e-5f) * g4.x + b4.x, 0.f);
            x1 = fmaxf((x1 + bi.y - m4.y) * rsqrtf(v4.y + 1e-5f) * g4.y + b4.y, 0.f);
            x2 = fmaxf((x2 + bi.z - m4.z) * rsqrtf(v4.z + 1e-5f) * g4.z + b4.z, 0.f);
            x3 = fmaxf((x3 + bi.w - m4.w) * rsqrtf(v4.w + 1e-5f) * g4.w + b4.w, 0.f);
        }
        ushort4 o; o.x = f2bf(x0); o.y = f2bf(x1); o.z = f2bf(x2); o.w = f2bf(x3);
        ((ushort4*)(dst + (size_t)d * HH))[tl] = o;
    }
}

__global__ __launch_bounds__(512) void k_mega(MegaArgs a) {
    __shared__ alignas(16) unsigned short As[2 * 8192];   // 32 KiB
    __shared__ alignas(16) unsigned short Bs[2 * 4096];   // 16 KiB
    int ph = 0;

    // A: G0 = featb @ W0a^T (direct bf16, no split-K)
    gemm_phase<0, false>(a.featb, a.w0at, NN, nullptr, nullptr, nullptr, nullptr, nullptr,
                         nullptr, nullptr, nullptr, nullptr, a.G0b, nullptr, nullptr, 0, As, Bs);
    gbar(a.bar, ++ph * NBLK);

    // B: agg0 -> xb
    agg_phase<true>(a.G0b, a.xb, a.starts, a.sorted, 1.0f + a.eps0[0],
                    a.b0a, a.bn0a_g, a.bn0a_b, a.bn0a_m, a.bn0a_v);
    gbar(a.bar, ++ph * NBLK);

    // C: h0 = MLP tail of layer 0 (+dot with WpR[0])
    gemm_phase<3, true>(a.xb, a.wt, HH, a.b0b,
                        a.bnA0_g, a.bnA0_b, a.bnA0_m, a.bnA0_v,
                        a.bnO0_g, a.bnO0_b, a.bnO0_m, a.bnO0_v,
                        a.hb, a.WpR, a.part, 4096 + blockIdx.x, As, Bs);
    gbar(a.bar, ++ph * NBLK);

    for (int L = 0; L < 3; ++L) {
        const unsigned short* hp = a.hb + (size_t)L * NN * HH;
        unsigned short* hn = (unsigned short*)a.hb + (size_t)(L + 1) * NN * HH;
        // D: aggregate
        agg_phase<false>(hp, a.xb, a.starts, a.sorted, 1.0f + a.epsR[L],
                         nullptr, nullptr, nullptr, nullptr, nullptr);
        gbar(a.bar, ++ph * NBLK);
        // E: first linear + BN + ReLU
        gemm_phase<1, false>(a.xb, a.wt + (size_t)(1 + L) * HH * HH, HH,
                             a.bRa + (size_t)L * HH,
                             a.bnRa_g + (size_t)L * HH, a.bnRa_b + (size_t)L * HH,
                             a.bnRa_m + (size_t)L * HH, a.bnRa_v + (size_t)L * HH,
                             nullptr, nullptr, nullptr, nullptr,
                             a.yb, nullptr, nullptr, 0, As, Bs);
        gbar(a.bar, ++ph * NBLK);
        // F: second linear + 2xBN/ReLU (+dot with WpR[L+1])
        gemm_phase<3, true>(a.yb, a.wt + (size_t)(4 + L) * HH * HH, HH,
                            a.bRb + (size_t)L * HH,
                            a.bnAR_g + (size_t)L * HH, a.bnAR_b + (size_t)L * HH,
                            a.bnAR_m + (size_t)L * HH, a.bnAR_v + (size_t)L * HH,
                            a.bnOR_g + (size_t)L * HH, a.bnOR_b + (size_t)L * HH,
                            a.bnOR_m + (size_t)L * HH, a.bnOR_v + (size_t)L * HH,
                            hn, a.WpR + (size_t)(L + 1) * NN * HH * 2,
                            a.part, 4096 + (L + 1) * 256 + blockIdx.x, As, Bs);
        gbar(a.bar, ++ph * NBLK);
    }

    // G: final jumping-knowledge reduce (block 0)
    if (blockIdx.x == 0) {
        const int t = threadIdx.x;
        float* r0 = (float*)As;
        float* r1 = r0 + 512;
        float aa0 = 0.f, aa1 = 0.f;
        for (int i = t; i < 5120; i += 512) { aa0 += a.part[2 * i]; aa1 += a.part[2 * i + 1]; }
        r0[t] = aa0; r1[t] = aa1;
        __syncthreads();
        for (int s = 256; s > 0; s >>= 1) {
            if (t < s) { r0[t] += r0[t + s]; r1[t] += r1[t + s]; }
            __syncthreads();
        }
        if (t == 0) {
            a.out[0] = r0[0] + a.bp0[0] + a.bpR[0] + a.bpR[2] + a.bpR[4] + a.bpR[6];
            a.out[1] = r1[0] + a.bp0[1] + a.bpR[1] + a.bpR[3] + a.bpR[5] + a.bpR[7];
        }
    }
}

extern "C" void kernel_launch(void* const* d_in, const int* in_sizes, int n_in,
                              void* d_out, int out_size, void* d_ws, size_t ws_size,
                              hipStream_t stream)
{
    const float* feat = (const float*)d_in[0];
    const int*   esrc = (const int*)d_in[1];
    const int*   edst = (const int*)d_in[2];
    const float* eps0 = (const float*)d_in[3];
    const float* W0a  = (const float*)d_in[4];
    const float* b0a  = (const float*)d_in[5];
    const float* W0b  = (const float*)d_in[6];
    const float* b0b  = (const float*)d_in[7];
    const float* bn0a_g = (const float*)d_in[8];
    const float* bn0a_b = (const float*)d_in[9];
    const float* bn0a_m = (const float*)d_in[10];
    const float* bn0a_v = (const float*)d_in[11];
    const float* bnA0_g = (const float*)d_in[12];
    const float* bnA0_b = (const float*)d_in[13];
    const float* bnA0_m = (const float*)d_in[14];
    const float* bnA0_v = (const float*)d_in[15];
    const float* bnO0_g = (const float*)d_in[16];
    const float* bnO0_b = (const float*)d_in[17];
    const float* bnO0_m = (const float*)d_in[18];
    const float* bnO0_v = (const float*)d_in[19];
    const float* epsR = (const float*)d_in[20];
    const float* WRa  = (const float*)d_in[21];
    const float* bRa  = (const float*)d_in[22];
    const float* WRb  = (const float*)d_in[23];
    const float* bRb  = (const float*)d_in[24];
    const float* bnRa_g = (const float*)d_in[25];
    const float* bnRa_b = (const float*)d_in[26];
    const float* bnRa_m = (const float*)d_in[27];
    const float* bnRa_v = (const float*)d_in[28];
    const float* bnAR_g = (const float*)d_in[29];
    const float* bnAR_b = (const float*)d_in[30];
    const float* bnAR_m = (const float*)d_in[31];
    const float* bnAR_v = (const float*)d_in[32];
    const float* bnOR_g = (const float*)d_in[33];
    const float* bnOR_b = (const float*)d_in[34];
    const float* bnOR_m = (const float*)d_in[35];
    const float* bnOR_v = (const float*)d_in[36];
    const float* Wp0 = (const float*)d_in[37];
    const float* bp0 = (const float*)d_in[38];
    const float* WpR = (const float*)d_in[39];
    const float* bpR = (const float*)d_in[40];
    float* out = (float*)d_out;

    char* ws = (char*)d_ws;
    const size_t MB = 1024 * 1024;
    int*   starts = (int*)(ws + 0x10000);     // [0x10000, 0x14004)
    int*   cursor = (int*)(ws + 0x20000);     // [0x20000, 0x24000)
    int*   bar    = (int*)(ws + 0x2C000);     // barrier counter (free hole, NOT in sorted!)
    int*   sorted = (int*)(ws + 0x30000);     // [0x30000, 0x70000) 256 KiB
    float* part   = (float*)(ws + 0x70000);   // 5120*2 f32 (40 KiB)
    unsigned short* featb = (unsigned short*)(ws + 1 * MB);    // [4096][4096] bf16, 32 MiB
    unsigned short* w0at  = (unsigned short*)(ws + 33 * MB);   // [512][4096] bf16, 4 MiB
    unsigned short* wt    = (unsigned short*)(ws + 37 * MB);   // 7 x [512][512] bf16
    unsigned short* G0b   = (unsigned short*)(ws + 41 * MB);   // [4096][512] bf16
    unsigned short* xb = (unsigned short*)(ws + 49 * MB);      // [4096][512] bf16
    unsigned short* yb = (unsigned short*)(ws + 53 * MB);      // [4096][512] bf16
    unsigned short* hb = (unsigned short*)(ws + 57 * MB);      // 4 x [4096][512] bf16

    // zero cursor + barrier counter (graph-replay safe: re-zeroed every call)
    hipMemsetAsync(ws + 0x20000, 0, 0x10000, stream);
    k_histscan<<<1, 1024, 0, stream>>>(edst, starts);
    k_scatter<<<EE / 256, 256, 0, stream>>>(esrc, edst, starts, cursor, sorted);
    k_binsort<<<NN / 256, 256, 0, stream>>>(starts, sorted);

    // prep: cvt feat + feat.Wp0 dot (blocks 0..4095) + 3840 weight-transpose tiles
    k_prep<<<4096 + 3840, 256, 0, stream>>>(feat, Wp0, featb, part,
                                            W0a, W0b, WRa, WRb, w0at, wt);

    MegaArgs a;
    a.featb = featb; a.w0at = w0at; a.wt = wt;
    a.G0b = G0b; a.xb = xb; a.yb = yb; a.hb = hb;
    a.starts = starts; a.sorted = sorted;
    a.eps0 = eps0; a.b0a = b0a;
    a.bn0a_g = bn0a_g; a.bn0a_b = bn0a_b; a.bn0a_m = bn0a_m; a.bn0a_v = bn0a_v;
    a.b0b = b0b;
    a.bnA0_g = bnA0_g; a.bnA0_b = bnA0_b; a.bnA0_m = bnA0_m; a.bnA0_v = bnA0_v;
    a.bnO0_g = bnO0_g; a.bnO0_b = bnO0_b; a.bnO0_m = bnO0_m; a.bnO0_v = bnO0_v;
    a.epsR = epsR; a.bRa = bRa;
    a.bnRa_g = bnRa_g; a.bnRa_b = bnRa_b; a.bnRa_m = bnRa_m; a.bnRa_v = bnRa_v;
    a.bRb = bRb;
    a.bnAR_g = bnAR_g; a.bnAR_b = bnAR_b; a.bnAR_m = bnAR_m; a.bnAR_v = bnAR_v;
    a.bnOR_g = bnOR_g; a.bnOR_b = bnOR_b; a.bnOR_m = bnOR_m; a.bnOR_v = bnOR_v;
    a.WpR = WpR; a.bp0 = bp0; a.bpR = bpR;
    a.part = part; a.out = out; a.bar = bar;

    k_mega<<<NBLK, 512, 0, stream>>>(a);
}

// Round 8
// 333.819 us; speedup vs baseline: 2.0385x; 2.0385x over previous
//
#include <hip/hip_runtime.h>
#include <cstdint>
#include <cstddef>

typedef __attribute__((ext_vector_type(8))) short short8;   // 8 bf16 (4 VGPRs)
typedef __attribute__((ext_vector_type(4))) float f32x4;    // 4 fp32 acc
typedef __attribute__((ext_vector_type(4))) float f4;
typedef __attribute__((ext_vector_type(2))) float f2;
typedef __attribute__((ext_vector_type(4))) unsigned short us4;

#define NN 4096
#define HH 512
#define EE 65536

// async global->LDS, 16B per lane (dest must be linear: base + lane*16)
#define GLOAD(gp, lp) __builtin_amdgcn_global_load_lds( \
    (const __attribute__((address_space(1))) void*)(gp), \
    (__attribute__((address_space(3))) void*)(lp), 16, 0, 0)

__device__ __forceinline__ unsigned short f2bf(float x) {
    union { float f; unsigned u; } un; un.f = x;
    unsigned r = un.u + 0x7fffu + ((un.u >> 16) & 1u);   // round-to-nearest-even
    return (unsigned short)(r >> 16);
}
__device__ __forceinline__ float b2f(unsigned short v) {
    union { unsigned u; float f; } un; un.u = ((unsigned)v) << 16; return un.f;
}

// ---------------- edge sort: fused hist+scan (1 block, also zeroes cursor) ----------------
__global__ __launch_bounds__(1024) void k_histscan(const int* __restrict__ edst,
                                                   int* __restrict__ starts,
                                                   int* __restrict__ cursor) {
    __shared__ int cnt[NN];
    __shared__ int wtot[16], woff[16];
    const int t = threadIdx.x;
    for (int i = t; i < NN; i += 1024) { cnt[i] = 0; cursor[i] = 0; }
    __syncthreads();
    for (int i = t; i < EE; i += 1024) atomicAdd(&cnt[edst[i]], 1);
    __syncthreads();
    const int b = t * 4;
    const int c0 = cnt[b], c1 = cnt[b + 1], c2 = cnt[b + 2], c3 = cnt[b + 3];
    const int s = c0 + c1 + c2 + c3;
    const int lane = t & 63, wv = t >> 6;
    int inc = s;
    for (int d = 1; d < 64; d <<= 1) {
        int v = __shfl_up(inc, d);
        if (lane >= d) inc += v;
    }
    if (lane == 63) wtot[wv] = inc;
    __syncthreads();
    if (t == 0) {
        int a = 0;
        for (int i = 0; i < 16; ++i) { woff[i] = a; a += wtot[i]; }
        starts[NN] = a;
    }
    __syncthreads();
    int run = woff[wv] + inc - s;
    starts[b] = run; run += c0;
    starts[b + 1] = run; run += c1;
    starts[b + 2] = run; run += c2;
    starts[b + 3] = run;
}

__global__ void k_scatter(const int* __restrict__ src, const int* __restrict__ dst,
                          const int* __restrict__ starts, int* __restrict__ cursor,
                          int* __restrict__ sorted) {
    int e = blockIdx.x * 256 + threadIdx.x;
    if (e < EE) {
        int d = dst[e];
        int p = starts[d] + atomicAdd(&cursor[d], 1);
        sorted[p] = src[e];
    }
}

__global__ void k_binsort(const int* __restrict__ starts, int* __restrict__ a) {
    int d = blockIdx.x * 256 + threadIdx.x;
    if (d < NN) {
        int s = starts[d], e = starts[d + 1];
        for (int i = s + 1; i < e; ++i) {
            int v = a[i]; int j = i - 1;
            while (j >= s && a[j] > v) { a[j + 1] = a[j]; --j; }
            a[j + 1] = v;
        }
    }
}

// ---------------- prep: blocks 0..4095 = cvt+dot0 slice; 4096.. = weight transposes ----------------
__global__ __launch_bounds__(256) void k_prep(const float* __restrict__ feat,
                                              const float* __restrict__ Wp0,
                                              unsigned short* __restrict__ featb,
                                              float* __restrict__ part,
                                              const float* __restrict__ W0a,
                                              const float* __restrict__ W0b,
                                              const float* __restrict__ WRa,
                                              const float* __restrict__ WRb,
                                              unsigned short* __restrict__ w0at,
                                              unsigned short* __restrict__ wt) {
    __shared__ f4 fs[1024];
    __shared__ float s0[256], s1[256];
    __shared__ float tile[32][33];
    const int t = threadIdx.x;
    const int bid = blockIdx.x;
    if (bid < 4096) {
        // ---- cvt + feat.Wp0 partial dot: block owns 1024 consecutive float4s ----
        const long B0 = (long)bid * 1024;
        const f4* ff = (const f4*)feat;
        const f4* ww = (const f4*)Wp0;
        f4 v[4];
#pragma unroll
        for (int k = 0; k < 4; ++k)
            v[k] = __builtin_nontemporal_load(ff + B0 + k * 256 + t);
#pragma unroll
        for (int k = 0; k < 4; ++k) {
            fs[k * 256 + t] = v[k];
            us4 o;
            o.x = f2bf(v[k].x); o.y = f2bf(v[k].y); o.z = f2bf(v[k].z); o.w = f2bf(v[k].w);
            __builtin_nontemporal_store(o, (us4*)featb + B0 + k * 256 + t);
        }
        f4 wv[8];
#pragma unroll
        for (int k = 0; k < 8; ++k)
            wv[k] = __builtin_nontemporal_load(ww + 2 * B0 + k * 256 + t);
        __syncthreads();
        float a0 = 0.f, a1 = 0.f;
#pragma unroll
        for (int k = 0; k < 8; ++k) {
            const int q = k * 256 + t;
            f2 fp = *(const f2*)((const char*)fs + (size_t)q * 8);
            a0 += fp.x * wv[k].x + fp.y * wv[k].z;
            a1 += fp.x * wv[k].y + fp.y * wv[k].w;
        }
        s0[t] = a0; s1[t] = a1;
        __syncthreads();
        for (int s = 128; s > 0; s >>= 1) {
            if (t < s) { s0[t] += s0[t + s]; s1[t] += s1[t + s]; }
            __syncthreads();
        }
        if (t == 0) { part[2 * bid] = s0[0]; part[2 * bid + 1] = s1[0]; }
    } else {
        // ---- weight transpose/convert tiles ----
        const int tix = bid - 4096;
        const float* W; unsigned short* Wt; int K, kb, nb;
        if (tix < 2048) {                 // W0a: 128 x 16 tiles of 32x32
            W = W0a; Wt = w0at; K = NN; kb = tix >> 4; nb = tix & 15;
        } else {
            const int t2 = tix - 2048;    // 7 x 256 tiles
            const int z = t2 >> 8, r = t2 & 255;
            W = (z == 0) ? W0b : (z < 4) ? WRa + (size_t)(z - 1) * HH * HH
                                         : WRb + (size_t)(z - 4) * HH * HH;
            Wt = wt + (size_t)z * HH * HH; K = HH; kb = r >> 4; nb = r & 15;
        }
        const int k0 = kb * 32, n0 = nb * 32;
        const int tx = t & 31, ty = t >> 5;
        for (int r = ty; r < 32; r += 8)
            tile[r][tx] = W[(size_t)(k0 + r) * HH + n0 + tx];
        __syncthreads();
        for (int r = ty; r < 32; r += 8)
            Wt[(size_t)(n0 + r) * K + k0 + tx] = f2bf(tile[tx][r]);
    }
}

// ---------------- GEMM: C = A[4096][K] @ Bt[512][K]^T, tile 64x64, 4 waves, BK=64 ----------------
// grid (64, 8) = 512 blocks (2 blocks/CU). Double-buffered LDS via global_load_lds.
// EPI 0: raw bf16. EPI 1: +bias,BN,ReLU -> bf16. EPI 3: +bias,BN,ReLU,BN,ReLU -> bf16 (+DOT).
template<int EPI, bool DOT>
__global__ __launch_bounds__(256) void k_gemmT(
    const unsigned short* __restrict__ A, const unsigned short* __restrict__ Bt, int K,
    const float* __restrict__ bias,
    const float* __restrict__ g1, const float* __restrict__ b1,
    const float* __restrict__ m1, const float* __restrict__ v1,
    const float* __restrict__ g2, const float* __restrict__ b2,
    const float* __restrict__ m2, const float* __restrict__ v2,
    unsigned short* __restrict__ outb,
    const float* __restrict__ wq, float* __restrict__ part, int slotbase)
{
    constexpr int N = HH;
    __shared__ alignas(16) unsigned short As[2 * 4096];   // 2 x 64x64 bf16 = 16 KiB
    __shared__ alignas(16) unsigned short Bs[2 * 4096];   // 16 KiB
    const int t = threadIdx.x;
    const int lane = t & 63, w = t >> 6;
    const int wr = w >> 1, wc = w & 1;                    // 2 row-waves x 2 col-waves
    const int l15 = lane & 15, l4 = lane >> 4;
    const int m0 = blockIdx.x * 64, n0 = blockIdx.y * 64;

    f32x4 acc[2][2];
#pragma unroll
    for (int i = 0; i < 2; ++i)
#pragma unroll
        for (int j = 0; j < 2; ++j) acc[i][j] = (f32x4){0.f, 0.f, 0.f, 0.f};

    // tile = 64 rows x 64 cols(2B) = 512 chunks of 16B; 256 threads -> 2 chunks each
    const unsigned short* ga0 = A + (size_t)(m0 + (t >> 3)) * K + (t & 7) * 8;
    const unsigned short* ga1 = ga0 + (size_t)32 * K;
    const unsigned short* gb0 = Bt + (size_t)(n0 + (t >> 3)) * K + (t & 7) * 8;
    const unsigned short* gb1 = gb0 + (size_t)32 * K;

    auto stage = [&](int kt, int buf) {
        const int ko = kt * 64;
        GLOAD(ga0 + ko, As + buf * 4096 + t * 8);
        GLOAD(ga1 + ko, As + buf * 4096 + 2048 + t * 8);
        GLOAD(gb0 + ko, Bs + buf * 4096 + t * 8);
        GLOAD(gb1 + ko, Bs + buf * 4096 + 2048 + t * 8);
    };

    const int nk = K >> 6;
    stage(0, 0);
    __syncthreads();                      // drains vmcnt: buf0 ready
    for (int kt = 0; kt < nk; ++kt) {
        const int cur = kt & 1;
        if (kt + 1 < nk) stage(kt + 1, cur ^ 1);
        const unsigned short* Ac = As + cur * 4096;
        const unsigned short* Bc = Bs + cur * 4096;
        short8 aF[2][2], bF[2][2];
#pragma unroll
        for (int i = 0; i < 2; ++i)
#pragma unroll
            for (int ks = 0; ks < 2; ++ks)
                aF[i][ks] = *(const short8*)(Ac + (wr * 32 + i * 16 + l15) * 64 + ks * 32 + l4 * 8);
#pragma unroll
        for (int j = 0; j < 2; ++j)
#pragma unroll
            for (int ks = 0; ks < 2; ++ks)
                bF[j][ks] = *(const short8*)(Bc + (wc * 32 + j * 16 + l15) * 64 + ks * 32 + l4 * 8);
#pragma unroll
        for (int ks = 0; ks < 2; ++ks)
#pragma unroll
            for (int i = 0; i < 2; ++i)
#pragma unroll
                for (int j = 0; j < 2; ++j)
                    acc[i][j] = __builtin_amdgcn_mfma_f32_16x16x32_bf16(aF[i][ks], bF[j][ks], acc[i][j], 0, 0, 0);
        __syncthreads();                  // next buffer ready, all frag reads done
    }

    const int mrow = m0 + wr * 32;
    float d0 = 0.f, d1 = 0.f;
#pragma unroll
    for (int j = 0; j < 2; ++j) {
        const int cg = n0 + wc * 32 + j * 16 + l15;
        float bi = 0.f, sc1 = 1.f, sh1 = 0.f, sc2 = 1.f, sh2 = 0.f;
        if (EPI >= 1) {
            bi = bias[cg];
            sc1 = rsqrtf(v1[cg] + 1e-5f) * g1[cg];
            sh1 = b1[cg] - m1[cg] * sc1;
        }
        if (EPI == 3) {
            sc2 = rsqrtf(v2[cg] + 1e-5f) * g2[cg];
            sh2 = b2[cg] - m2[cg] * sc2;
        }
#pragma unroll
        for (int i = 0; i < 2; ++i) {
#pragma unroll
            for (int r = 0; r < 4; ++r) {
                const int rg = mrow + i * 16 + l4 * 4 + r;
                float x = acc[i][j][r];
                if (EPI >= 1) {
                    x = fmaxf((x + bi) * sc1 + sh1, 0.f);
                    if (EPI == 3) x = fmaxf(x * sc2 + sh2, 0.f);
                }
                outb[(size_t)rg * N + cg] = f2bf(x);
                if constexpr (DOT) {
                    f2 wvv = __builtin_nontemporal_load((const f2*)wq + (size_t)rg * N + cg);
                    d0 += x * wvv.x; d1 += x * wvv.y;
                }
            }
        }
    }
    if constexpr (DOT) {
        float* r0 = (float*)As;           // LDS scratch (frag reads all done)
        float* r1 = r0 + 256;
        __syncthreads();
        r0[t] = d0; r1[t] = d1;
        __syncthreads();
        for (int s = 128; s > 0; s >>= 1) {
            if (t < s) { r0[t] += r0[t + s]; r1[t] += r1[t + s]; }
            __syncthreads();
        }
        if (t == 0) {
            const int slot = slotbase + blockIdx.y * gridDim.x + blockIdx.x;
            part[2 * slot] = r0[0]; part[2 * slot + 1] = r1[0];
        }
    }
}

// ---------------- edge aggregation (gather-sum over sorted in-edges, 4x prefetch) ----------------
__global__ __launch_bounds__(128) void k_agg0(
    const unsigned short* __restrict__ G0, const int* __restrict__ starts,
    const int* __restrict__ sorted, const float* __restrict__ epsp,
    const float* __restrict__ bias,
    const float* __restrict__ bg, const float* __restrict__ bb,
    const float* __restrict__ bm, const float* __restrict__ bv,
    unsigned short* __restrict__ outb)
{
    const int d = blockIdx.x, t = threadIdx.x;
    const float ep = 1.0f + epsp[0];
    ushort4 ow = ((const ushort4*)(G0 + (size_t)d * HH))[t];
    float sx = 0.f, sy = 0.f, sz = 0.f, sw = 0.f;
    const int e0 = starts[d], e1 = starts[d + 1];
    int i = e0;
    for (; i + 4 <= e1; i += 4) {
        int q0 = sorted[i], q1 = sorted[i + 1], q2 = sorted[i + 2], q3 = sorted[i + 3];
        ushort4 x0 = ((const ushort4*)(G0 + (size_t)q0 * HH))[t];
        ushort4 x1 = ((const ushort4*)(G0 + (size_t)q1 * HH))[t];
        ushort4 x2 = ((const ushort4*)(G0 + (size_t)q2 * HH))[t];
        ushort4 x3 = ((const ushort4*)(G0 + (size_t)q3 * HH))[t];
        sx += (b2f(x0.x) + b2f(x1.x)) + (b2f(x2.x) + b2f(x3.x));
        sy += (b2f(x0.y) + b2f(x1.y)) + (b2f(x2.y) + b2f(x3.y));
        sz += (b2f(x0.z) + b2f(x1.z)) + (b2f(x2.z) + b2f(x3.z));
        sw += (b2f(x0.w) + b2f(x1.w)) + (b2f(x2.w) + b2f(x3.w));
    }
    for (; i < e1; ++i) {
        ushort4 x = ((const ushort4*)(G0 + (size_t)sorted[i] * HH))[t];
        sx += b2f(x.x); sy += b2f(x.y); sz += b2f(x.z); sw += b2f(x.w);
    }
    float4 bi = ((const float4*)bias)[t];
    float4 g4 = ((const float4*)bg)[t];
    float4 b4 = ((const float4*)bb)[t];
    float4 m4 = ((const float4*)bm)[t];
    float4 v4 = ((const float4*)bv)[t];
    float x0 = ep * b2f(ow.x) + sx + bi.x;
    float x1 = ep * b2f(ow.y) + sy + bi.y;
    float x2 = ep * b2f(ow.z) + sz + bi.z;
    float x3 = ep * b2f(ow.w) + sw + bi.w;
    x0 = fmaxf((x0 - m4.x) * rsqrtf(v4.x + 1e-5f) * g4.x + b4.x, 0.f);
    x1 = fmaxf((x1 - m4.y) * rsqrtf(v4.y + 1e-5f) * g4.y + b4.y, 0.f);
    x2 = fmaxf((x2 - m4.z) * rsqrtf(v4.z + 1e-5f) * g4.z + b4.z, 0.f);
    x3 = fmaxf((x3 - m4.w) * rsqrtf(v4.w + 1e-5f) * g4.w + b4.w, 0.f);
    ushort4 o; o.x = f2bf(x0); o.y = f2bf(x1); o.z = f2bf(x2); o.w = f2bf(x3);
    ((ushort4*)(outb + (size_t)d * HH))[t] = o;
}

__global__ __launch_bounds__(128) void k_aggL(
    const unsigned short* __restrict__ hsrc, const int* __restrict__ starts,
    const int* __restrict__ sorted, const float* __restrict__ epsp,
    unsigned short* __restrict__ outb)
{
    const int d = blockIdx.x, t = threadIdx.x;
    const float ep = 1.0f + epsp[0];
    ushort4 ow = ((const ushort4*)(hsrc + (size_t)d * HH))[t];
    float sx = 0.f, sy = 0.f, sz = 0.f, sw = 0.f;
    const int e0 = starts[d], e1 = starts[d + 1];
    int i = e0;
    for (; i + 4 <= e1; i += 4) {
        int q0 = sorted[i], q1 = sorted[i + 1], q2 = sorted[i + 2], q3 = sorted[i + 3];
        ushort4 x0 = ((const ushort4*)(hsrc + (size_t)q0 * HH))[t];
        ushort4 x1 = ((const ushort4*)(hsrc + (size_t)q1 * HH))[t];
        ushort4 x2 = ((const ushort4*)(hsrc + (size_t)q2 * HH))[t];
        ushort4 x3 = ((const ushort4*)(hsrc + (size_t)q3 * HH))[t];
        sx += (b2f(x0.x) + b2f(x1.x)) + (b2f(x2.x) + b2f(x3.x));
        sy += (b2f(x0.y) + b2f(x1.y)) + (b2f(x2.y) + b2f(x3.y));
        sz += (b2f(x0.z) + b2f(x1.z)) + (b2f(x2.z) + b2f(x3.z));
        sw += (b2f(x0.w) + b2f(x1.w)) + (b2f(x2.w) + b2f(x3.w));
    }
    for (; i < e1; ++i) {
        ushort4 x = ((const ushort4*)(hsrc + (size_t)sorted[i] * HH))[t];
        sx += b2f(x.x); sy += b2f(x.y); sz += b2f(x.z); sw += b2f(x.w);
    }
    ushort4 o;
    o.x = f2bf(ep * b2f(ow.x) + sx);
    o.y = f2bf(ep * b2f(ow.y) + sy);
    o.z = f2bf(ep * b2f(ow.z) + sz);
    o.w = f2bf(ep * b2f(ow.w) + sw);
    ((ushort4*)(outb + (size_t)d * HH))[t] = o;
}

__global__ __launch_bounds__(256) void k_final(const float* __restrict__ part, int nslot,
                                               const float* __restrict__ bp0, const float* __restrict__ bpR,
                                               float* __restrict__ out) {
    __shared__ float s0[256], s1[256];
    int t = threadIdx.x;
    float a0 = 0.f, a1 = 0.f;
    for (int i = t; i < nslot; i += 256) { a0 += part[2 * i]; a1 += part[2 * i + 1]; }
    s0[t] = a0; s1[t] = a1;
    __syncthreads();
    for (int s = 128; s > 0; s >>= 1) {
        if (t < s) { s0[t] += s0[t + s]; s1[t] += s1[t + s]; }
        __syncthreads();
    }
    if (t == 0) {
        out[0] = s0[0] + bp0[0] + bpR[0] + bpR[2] + bpR[4] + bpR[6];
        out[1] = s1[0] + bp0[1] + bpR[1] + bpR[3] + bpR[5] + bpR[7];
    }
}

extern "C" void kernel_launch(void* const* d_in, const int* in_sizes, int n_in,
                              void* d_out, int out_size, void* d_ws, size_t ws_size,
                              hipStream_t stream)
{
    const float* feat = (const float*)d_in[0];
    const int*   esrc = (const int*)d_in[1];
    const int*   edst = (const int*)d_in[2];
    const float* eps0 = (const float*)d_in[3];
    const float* W0a  = (const float*)d_in[4];
    const float* b0a  = (const float*)d_in[5];
    const float* W0b  = (const float*)d_in[6];
    const float* b0b  = (const float*)d_in[7];
    const float* bn0a_g = (const float*)d_in[8];
    const float* bn0a_b = (const float*)d_in[9];
    const float* bn0a_m = (const float*)d_in[10];
    const float* bn0a_v = (const float*)d_in[11];
    const float* bnA0_g = (const float*)d_in[12];
    const float* bnA0_b = (const float*)d_in[13];
    const float* bnA0_m = (const float*)d_in[14];
    const float* bnA0_v = (const float*)d_in[15];
    const float* bnO0_g = (const float*)d_in[16];
    const float* bnO0_b = (const float*)d_in[17];
    const float* bnO0_m = (const float*)d_in[18];
    const float* bnO0_v = (const float*)d_in[19];
    const float* epsR = (const float*)d_in[20];
    const float* WRa  = (const float*)d_in[21];
    const float* bRa  = (const float*)d_in[22];
    const float* WRb  = (const float*)d_in[23];
    const float* bRb  = (const float*)d_in[24];
    const float* bnRa_g = (const float*)d_in[25];
    const float* bnRa_b = (const float*)d_in[26];
    const float* bnRa_m = (const float*)d_in[27];
    const float* bnRa_v = (const float*)d_in[28];
    const float* bnAR_g = (const float*)d_in[29];
    const float* bnAR_b = (const float*)d_in[30];
    const float* bnAR_m = (const float*)d_in[31];
    const float* bnAR_v = (const float*)d_in[32];
    const float* bnOR_g = (const float*)d_in[33];
    const float* bnOR_b = (const float*)d_in[34];
    const float* bnOR_m = (const float*)d_in[35];
    const float* bnOR_v = (const float*)d_in[36];
    const float* Wp0 = (const float*)d_in[37];
    const float* bp0 = (const float*)d_in[38];
    const float* WpR = (const float*)d_in[39];
    const float* bpR = (const float*)d_in[40];
    float* out = (float*)d_out;

    char* ws = (char*)d_ws;
    const size_t MB = 1024 * 1024;
    int*   starts = (int*)(ws + 0x10000);     // [0x10000, 0x14004)
    int*   cursor = (int*)(ws + 0x20000);     // [0x20000, 0x24000)
    int*   sorted = (int*)(ws + 0x30000);     // [0x30000, 0x70000) 256 KiB
    float* part   = (float*)(ws + 0x70000);   // 6144*2 f32 (48 KiB)
    unsigned short* featb = (unsigned short*)(ws + 1 * MB);    // [4096][4096] bf16, 32 MiB
    unsigned short* w0at  = (unsigned short*)(ws + 33 * MB);   // [512][4096] bf16, 4 MiB
    unsigned short* wt    = (unsigned short*)(ws + 37 * MB);   // 7 x [512][512] bf16
    unsigned short* G0b   = (unsigned short*)(ws + 41 * MB);   // [4096][512] bf16
    unsigned short* xb = (unsigned short*)(ws + 49 * MB);      // [4096][512] bf16
    unsigned short* yb = (unsigned short*)(ws + 53 * MB);      // [4096][512] bf16
    unsigned short* hb = (unsigned short*)(ws + 57 * MB);      // 4 x [4096][512] bf16

    // ---- edge sort (histscan zeroes cursor; no memset dispatch) ----
    k_histscan<<<1, 1024, 0, stream>>>(edst, starts, cursor);
    k_scatter<<<EE / 256, 256, 0, stream>>>(esrc, edst, starts, cursor, sorted);
    k_binsort<<<NN / 256, 256, 0, stream>>>(starts, sorted);

    // ---- prep: cvt feat + feat.Wp0 dot (blocks 0..4095) + 3840 weight-transpose tiles ----
    k_prep<<<4096 + 3840, 256, 0, stream>>>(feat, Wp0, featb, part,
                                            W0a, W0b, WRa, WRb, w0at, wt);

    const dim3 gg(NN / 64, HH / 64);   // 512 blocks, 2 per CU

    // ---- layer 0 (reassociated: G0 = feat@W0a first, then aggregate) ----
    k_gemmT<0, false><<<gg, 256, 0, stream>>>(featb, w0at, NN,
        nullptr, nullptr, nullptr, nullptr, nullptr, nullptr, nullptr, nullptr, nullptr,
        G0b, nullptr, nullptr, 0);
    k_agg0<<<NN, 128, 0, stream>>>(G0b, starts, sorted, eps0, b0a,
                                   bn0a_g, bn0a_b, bn0a_m, bn0a_v, xb);
    k_gemmT<3, true><<<gg, 256, 0, stream>>>(xb, wt, HH,
        b0b, bnA0_g, bnA0_b, bnA0_m, bnA0_v, bnO0_g, bnO0_b, bnO0_m, bnO0_v,
        hb, WpR, part, 4096);

    // ---- layers 1..3 ----
    for (int i = 0; i < 3; ++i) {
        const unsigned short* hp = hb + (size_t)i * NN * HH;
        unsigned short* hn = hb + (size_t)(i + 1) * NN * HH;
        k_aggL<<<NN, 128, 0, stream>>>(hp, starts, sorted, epsR + i, xb);
        k_gemmT<1, false><<<gg, 256, 0, stream>>>(xb, wt + (size_t)(1 + i) * HH * HH, HH,
            bRa + (size_t)i * HH,
            bnRa_g + (size_t)i * HH, bnRa_b + (size_t)i * HH, bnRa_m + (size_t)i * HH, bnRa_v + (size_t)i * HH,
            nullptr, nullptr, nullptr, nullptr,
            yb, nullptr, nullptr, 0);
        k_gemmT<3, true><<<gg, 256, 0, stream>>>(yb, wt + (size_t)(4 + i) * HH * HH, HH,
            bRb + (size_t)i * HH,
            bnAR_g + (size_t)i * HH, bnAR_b + (size_t)i * HH, bnAR_m + (size_t)i * HH, bnAR_v + (size_t)i * HH,
            bnOR_g + (size_t)i * HH, bnOR_b + (size_t)i * HH, bnOR_m + (size_t)i * HH, bnOR_v + (size_t)i * HH,
            hn, WpR + (size_t)(i + 1) * NN * HH * 2, part, 4096 + (i + 1) * 512);
    }

    // ---- jumping-knowledge readout final reduce ----
    k_final<<<1, 256, 0, stream>>>(part, 4096 + 4 * 512, bp0, bpR, out);
}

// Round 9
// 308.979 us; speedup vs baseline: 2.2024x; 1.0804x over previous
//
#include <hip/hip_runtime.h>
#include <cstdint>
#include <cstddef>

typedef __attribute__((ext_vector_type(8))) short short8;   // 8 bf16 (4 VGPRs)
typedef __attribute__((ext_vector_type(4))) float f32x4;    // 4 fp32 acc
typedef __attribute__((ext_vector_type(4))) float f4;
typedef __attribute__((ext_vector_type(2))) float f2;
typedef __attribute__((ext_vector_type(4))) unsigned short us4;

#define NN 4096
#define HH 512
#define EE 65536

// async global->LDS, 16B per lane (dest must be linear: base + lane*16)
#define GLOAD(gp, lp) __builtin_amdgcn_global_load_lds( \
    (const __attribute__((address_space(1))) void*)(gp), \
    (__attribute__((address_space(3))) void*)(lp), 16, 0, 0)

__device__ __forceinline__ unsigned short f2bf(float x) {
    union { float f; unsigned u; } un; un.f = x;
    unsigned r = un.u + 0x7fffu + ((un.u >> 16) & 1u);   // round-to-nearest-even
    return (unsigned short)(r >> 16);
}
__device__ __forceinline__ float b2f(unsigned short v) {
    union { unsigned u; float f; } un; un.u = ((unsigned)v) << 16; return un.f;
}

// ---------------- edge sort: fused hist+scan (1 block, also zeroes cursor) ----------------
__global__ __launch_bounds__(1024) void k_histscan(const int* __restrict__ edst,
                                                   int* __restrict__ starts,
                                                   int* __restrict__ cursor) {
    __shared__ int cnt[NN];
    __shared__ int wtot[16], woff[16];
    const int t = threadIdx.x;
    for (int i = t; i < NN; i += 1024) { cnt[i] = 0; cursor[i] = 0; }
    __syncthreads();
    for (int i = t; i < EE; i += 1024) atomicAdd(&cnt[edst[i]], 1);
    __syncthreads();
    const int b = t * 4;
    const int c0 = cnt[b], c1 = cnt[b + 1], c2 = cnt[b + 2], c3 = cnt[b + 3];
    const int s = c0 + c1 + c2 + c3;
    const int lane = t & 63, wv = t >> 6;
    int inc = s;
    for (int d = 1; d < 64; d <<= 1) {
        int v = __shfl_up(inc, d);
        if (lane >= d) inc += v;
    }
    if (lane == 63) wtot[wv] = inc;
    __syncthreads();
    if (t == 0) {
        int a = 0;
        for (int i = 0; i < 16; ++i) { woff[i] = a; a += wtot[i]; }
        starts[NN] = a;
    }
    __syncthreads();
    int run = woff[wv] + inc - s;
    starts[b] = run; run += c0;
    starts[b + 1] = run; run += c1;
    starts[b + 2] = run; run += c2;
    starts[b + 3] = run;
}

__global__ void k_scatter(const int* __restrict__ src, const int* __restrict__ dst,
                          const int* __restrict__ starts, int* __restrict__ cursor,
                          int* __restrict__ sorted) {
    int e = blockIdx.x * 256 + threadIdx.x;
    if (e < EE) {
        int d = dst[e];
        int p = starts[d] + atomicAdd(&cursor[d], 1);
        sorted[p] = src[e];
    }
}

__global__ void k_binsort(const int* __restrict__ starts, int* __restrict__ a) {
    int d = blockIdx.x * 256 + threadIdx.x;
    if (d < NN) {
        int s = starts[d], e = starts[d + 1];
        for (int i = s + 1; i < e; ++i) {
            int v = a[i]; int j = i - 1;
            while (j >= s && a[j] > v) { a[j + 1] = a[j]; --j; }
            a[j + 1] = v;
        }
    }
}

// ---------------- prep: blocks 0..4095 = cvt+dot0 slice; 4096.. = weight transposes ----------------
__global__ __launch_bounds__(256) void k_prep(const float* __restrict__ feat,
                                              const float* __restrict__ Wp0,
                                              unsigned short* __restrict__ featb,
                                              float* __restrict__ part,
                                              const float* __restrict__ W0a,
                                              const float* __restrict__ W0b,
                                              const float* __restrict__ WRa,
                                              const float* __restrict__ WRb,
                                              unsigned short* __restrict__ w0at,
                                              unsigned short* __restrict__ wt) {
    __shared__ f4 fs[1024];
    __shared__ float s0[256], s1[256];
    __shared__ float tile[32][33];
    const int t = threadIdx.x;
    const int bid = blockIdx.x;
    if (bid < 4096) {
        // ---- cvt + feat.Wp0 partial dot: block owns 1024 consecutive float4s ----
        const long B0 = (long)bid * 1024;
        const f4* ff = (const f4*)feat;
        const f4* ww = (const f4*)Wp0;
        f4 v[4];
#pragma unroll
        for (int k = 0; k < 4; ++k)
            v[k] = __builtin_nontemporal_load(ff + B0 + k * 256 + t);
#pragma unroll
        for (int k = 0; k < 4; ++k) {
            fs[k * 256 + t] = v[k];
            us4 o;
            o.x = f2bf(v[k].x); o.y = f2bf(v[k].y); o.z = f2bf(v[k].z); o.w = f2bf(v[k].w);
            __builtin_nontemporal_store(o, (us4*)featb + B0 + k * 256 + t);
        }
        f4 wv[8];
#pragma unroll
        for (int k = 0; k < 8; ++k)
            wv[k] = __builtin_nontemporal_load(ww + 2 * B0 + k * 256 + t);
        __syncthreads();
        float a0 = 0.f, a1 = 0.f;
#pragma unroll
        for (int k = 0; k < 8; ++k) {
            const int q = k * 256 + t;
            f2 fp = *(const f2*)((const char*)fs + (size_t)q * 8);
            a0 += fp.x * wv[k].x + fp.y * wv[k].z;
            a1 += fp.x * wv[k].y + fp.y * wv[k].w;
        }
        s0[t] = a0; s1[t] = a1;
        __syncthreads();
        for (int s = 128; s > 0; s >>= 1) {
            if (t < s) { s0[t] += s0[t + s]; s1[t] += s1[t + s]; }
            __syncthreads();
        }
        if (t == 0) { part[2 * bid] = s0[0]; part[2 * bid + 1] = s1[0]; }
    } else {
        // ---- weight transpose/convert tiles ----
        const int tix = bid - 4096;
        const float* W; unsigned short* Wt; int K, kb, nb;
        if (tix < 2048) {                 // W0a: 128 x 16 tiles of 32x32
            W = W0a; Wt = w0at; K = NN; kb = tix >> 4; nb = tix & 15;
        } else {
            const int t2 = tix - 2048;    // 7 x 256 tiles
            const int z = t2 >> 8, r = t2 & 255;
            W = (z == 0) ? W0b : (z < 4) ? WRa + (size_t)(z - 1) * HH * HH
                                         : WRb + (size_t)(z - 4) * HH * HH;
            Wt = wt + (size_t)z * HH * HH; K = HH; kb = r >> 4; nb = r & 15;
        }
        const int k0 = kb * 32, n0 = nb * 32;
        const int tx = t & 31, ty = t >> 5;
        for (int r = ty; r < 32; r += 8)
            tile[r][tx] = W[(size_t)(k0 + r) * HH + n0 + tx];
        __syncthreads();
        for (int r = ty; r < 32; r += 8)
            Wt[(size_t)(n0 + r) * K + k0 + tx] = f2bf(tile[tx][r]);
    }
}

// ---------------- GEMM: C = A[4096][K] @ Bt[512][K]^T, tile 64x64, 4 waves, BK=64 ----------------
// grid (64, 8) = 512 blocks (2 blocks/CU). Double-buffered LDS via global_load_lds.
// LDS tile is XOR-SWIZZLED: slot (row, s) holds global chunk (row, s ^ (row&7)).
// global_load_lds writes linearly, so the PERMUTED chunk is fetched at the source
// (thread t loads chunk (t&7)^((t>>3)&7) of its row); reads XOR the slot the same way.
// Bank math: byte = row*128 + slot*16 -> bank = 4*slot; slot spans all 8 values across
// l15&7 -> 8 disjoint 4-bank groups, 2 lanes each = conflict-free (was 16-way).
// EPI 0: raw bf16. EPI 1: +bias,BN,ReLU -> bf16. EPI 3: +bias,BN,ReLU,BN,ReLU -> bf16 (+DOT).
template<int EPI, bool DOT>
__global__ __launch_bounds__(256) void k_gemmT(
    const unsigned short* __restrict__ A, const unsigned short* __restrict__ Bt, int K,
    const float* __restrict__ bias,
    const float* __restrict__ g1, const float* __restrict__ b1,
    const float* __restrict__ m1, const float* __restrict__ v1,
    const float* __restrict__ g2, const float* __restrict__ b2,
    const float* __restrict__ m2, const float* __restrict__ v2,
    unsigned short* __restrict__ outb,
    const float* __restrict__ wq, float* __restrict__ part, int slotbase)
{
    constexpr int N = HH;
    __shared__ alignas(16) unsigned short As[2 * 4096];   // 2 x 64x64 bf16 = 16 KiB
    __shared__ alignas(16) unsigned short Bs[2 * 4096];   // 16 KiB
    const int t = threadIdx.x;
    const int lane = t & 63, w = t >> 6;
    const int wr = w >> 1, wc = w & 1;                    // 2 row-waves x 2 col-waves
    const int l15 = lane & 15, l4 = lane >> 4;
    const int m0 = blockIdx.x * 64, n0 = blockIdx.y * 64;

    f32x4 acc[2][2];
#pragma unroll
    for (int i = 0; i < 2; ++i)
#pragma unroll
        for (int j = 0; j < 2; ++j) acc[i][j] = (f32x4){0.f, 0.f, 0.f, 0.f};

    // tile = 64 rows x 8 chunks(16B); thread t owns LDS slots (t>>3, t&7) and (+32 rows).
    // source chunk is the swizzled one; +32*K stays valid since 32 % 8 == 0.
    const int ar = t >> 3;
    const int ac = (t & 7) ^ (ar & 7);
    const unsigned short* ga0 = A + (size_t)(m0 + ar) * K + ac * 8;
    const unsigned short* ga1 = ga0 + (size_t)32 * K;
    const unsigned short* gb0 = Bt + (size_t)(n0 + ar) * K + ac * 8;
    const unsigned short* gb1 = gb0 + (size_t)32 * K;

    auto stage = [&](int kt, int buf) {
        const int ko = kt * 64;
        GLOAD(ga0 + ko, As + buf * 4096 + t * 8);
        GLOAD(ga1 + ko, As + buf * 4096 + 2048 + t * 8);
        GLOAD(gb0 + ko, Bs + buf * 4096 + t * 8);
        GLOAD(gb1 + ko, Bs + buf * 4096 + 2048 + t * 8);
    };

    const int rsw = l15 & 7;              // read-side XOR key (row & 7)
    const int nk = K >> 6;
    stage(0, 0);
    __syncthreads();                      // drains vmcnt: buf0 ready
    for (int kt = 0; kt < nk; ++kt) {
        const int cur = kt & 1;
        if (kt + 1 < nk) stage(kt + 1, cur ^ 1);
        const unsigned short* Ac = As + cur * 4096;
        const unsigned short* Bc = Bs + cur * 4096;
        short8 aF[2][2], bF[2][2];
#pragma unroll
        for (int i = 0; i < 2; ++i)
#pragma unroll
            for (int ks = 0; ks < 2; ++ks)
                aF[i][ks] = *(const short8*)(Ac + (wr * 32 + i * 16 + l15) * 64
                                                + (((ks * 4 + l4) ^ rsw) * 8));
#pragma unroll
        for (int j = 0; j < 2; ++j)
#pragma unroll
            for (int ks = 0; ks < 2; ++ks)
                bF[j][ks] = *(const short8*)(Bc + (wc * 32 + j * 16 + l15) * 64
                                                + (((ks * 4 + l4) ^ rsw) * 8));
#pragma unroll
        for (int ks = 0; ks < 2; ++ks)
#pragma unroll
            for (int i = 0; i < 2; ++i)
#pragma unroll
                for (int j = 0; j < 2; ++j)
                    acc[i][j] = __builtin_amdgcn_mfma_f32_16x16x32_bf16(aF[i][ks], bF[j][ks], acc[i][j], 0, 0, 0);
        __syncthreads();                  // next buffer ready, all frag reads done
    }

    const int mrow = m0 + wr * 32;
    float d0 = 0.f, d1 = 0.f;
#pragma unroll
    for (int j = 0; j < 2; ++j) {
        const int cg = n0 + wc * 32 + j * 16 + l15;
        float bi = 0.f, sc1 = 1.f, sh1 = 0.f, sc2 = 1.f, sh2 = 0.f;
        if (EPI >= 1) {
            bi = bias[cg];
            sc1 = rsqrtf(v1[cg] + 1e-5f) * g1[cg];
            sh1 = b1[cg] - m1[cg] * sc1;
        }
        if (EPI == 3) {
            sc2 = rsqrtf(v2[cg] + 1e-5f) * g2[cg];
            sh2 = b2[cg] - m2[cg] * sc2;
        }
#pragma unroll
        for (int i = 0; i < 2; ++i) {
#pragma unroll
            for (int r = 0; r < 4; ++r) {
                const int rg = mrow + i * 16 + l4 * 4 + r;
                float x = acc[i][j][r];
                if (EPI >= 1) {
                    x = fmaxf((x + bi) * sc1 + sh1, 0.f);
                    if (EPI == 3) x = fmaxf(x * sc2 + sh2, 0.f);
                }
                outb[(size_t)rg * N + cg] = f2bf(x);
                if constexpr (DOT) {
                    f2 wvv = __builtin_nontemporal_load((const f2*)wq + (size_t)rg * N + cg);
                    d0 += x * wvv.x; d1 += x * wvv.y;
                }
            }
        }
    }
    if constexpr (DOT) {
        float* r0 = (float*)As;           // LDS scratch (frag reads all done)
        float* r1 = r0 + 256;
        __syncthreads();
        r0[t] = d0; r1[t] = d1;
        __syncthreads();
        for (int s = 128; s > 0; s >>= 1) {
            if (t < s) { r0[t] += r0[t + s]; r1[t] += r1[t + s]; }
            __syncthreads();
        }
        if (t == 0) {
            const int slot = slotbase + blockIdx.y * gridDim.x + blockIdx.x;
            part[2 * slot] = r0[0]; part[2 * slot + 1] = r1[0];
        }
    }
}

// ---------------- edge aggregation (gather-sum over sorted in-edges, 4x prefetch) ----------------
__global__ __launch_bounds__(128) void k_agg0(
    const unsigned short* __restrict__ G0, const int* __restrict__ starts,
    const int* __restrict__ sorted, const float* __restrict__ epsp,
    const float* __restrict__ bias,
    const float* __restrict__ bg, const float* __restrict__ bb,
    const float* __restrict__ bm, const float* __restrict__ bv,
    unsigned short* __restrict__ outb)
{
    const int d = blockIdx.x, t = threadIdx.x;
    const float ep = 1.0f + epsp[0];
    ushort4 ow = ((const ushort4*)(G0 + (size_t)d * HH))[t];
    float sx = 0.f, sy = 0.f, sz = 0.f, sw = 0.f;
    const int e0 = starts[d], e1 = starts[d + 1];
    int i = e0;
    for (; i + 4 <= e1; i += 4) {
        int q0 = sorted[i], q1 = sorted[i + 1], q2 = sorted[i + 2], q3 = sorted[i + 3];
        ushort4 x0 = ((const ushort4*)(G0 + (size_t)q0 * HH))[t];
        ushort4 x1 = ((const ushort4*)(G0 + (size_t)q1 * HH))[t];
        ushort4 x2 = ((const ushort4*)(G0 + (size_t)q2 * HH))[t];
        ushort4 x3 = ((const ushort4*)(G0 + (size_t)q3 * HH))[t];
        sx += (b2f(x0.x) + b2f(x1.x)) + (b2f(x2.x) + b2f(x3.x));
        sy += (b2f(x0.y) + b2f(x1.y)) + (b2f(x2.y) + b2f(x3.y));
        sz += (b2f(x0.z) + b2f(x1.z)) + (b2f(x2.z) + b2f(x3.z));
        sw += (b2f(x0.w) + b2f(x1.w)) + (b2f(x2.w) + b2f(x3.w));
    }
    for (; i < e1; ++i) {
        ushort4 x = ((const ushort4*)(G0 + (size_t)sorted[i] * HH))[t];
        sx += b2f(x.x); sy += b2f(x.y); sz += b2f(x.z); sw += b2f(x.w);
    }
    float4 bi = ((const float4*)bias)[t];
    float4 g4 = ((const float4*)bg)[t];
    float4 b4 = ((const float4*)bb)[t];
    float4 m4 = ((const float4*)bm)[t];
    float4 v4 = ((const float4*)bv)[t];
    float x0 = ep * b2f(ow.x) + sx + bi.x;
    float x1 = ep * b2f(ow.y) + sy + bi.y;
    float x2 = ep * b2f(ow.z) + sz + bi.z;
    float x3 = ep * b2f(ow.w) + sw + bi.w;
    x0 = fmaxf((x0 - m4.x) * rsqrtf(v4.x + 1e-5f) * g4.x + b4.x, 0.f);
    x1 = fmaxf((x1 - m4.y) * rsqrtf(v4.y + 1e-5f) * g4.y + b4.y, 0.f);
    x2 = fmaxf((x2 - m4.z) * rsqrtf(v4.z + 1e-5f) * g4.z + b4.z, 0.f);
    x3 = fmaxf((x3 - m4.w) * rsqrtf(v4.w + 1e-5f) * g4.w + b4.w, 0.f);
    ushort4 o; o.x = f2bf(x0); o.y = f2bf(x1); o.z = f2bf(x2); o.w = f2bf(x3);
    ((ushort4*)(outb + (size_t)d * HH))[t] = o;
}

__global__ __launch_bounds__(128) void k_aggL(
    const unsigned short* __restrict__ hsrc, const int* __restrict__ starts,
    const int* __restrict__ sorted, const float* __restrict__ epsp,
    unsigned short* __restrict__ outb)
{
    const int d = blockIdx.x, t = threadIdx.x;
    const float ep = 1.0f + epsp[0];
    ushort4 ow = ((const ushort4*)(hsrc + (size_t)d * HH))[t];
    float sx = 0.f, sy = 0.f, sz = 0.f, sw = 0.f;
    const int e0 = starts[d], e1 = starts[d + 1];
    int i = e0;
    for (; i + 4 <= e1; i += 4) {
        int q0 = sorted[i], q1 = sorted[i + 1], q2 = sorted[i + 2], q3 = sorted[i + 3];
        ushort4 x0 = ((const ushort4*)(hsrc + (size_t)q0 * HH))[t];
        ushort4 x1 = ((const ushort4*)(hsrc + (size_t)q1 * HH))[t];
        ushort4 x2 = ((const ushort4*)(hsrc + (size_t)q2 * HH))[t];
        ushort4 x3 = ((const ushort4*)(hsrc + (size_t)q3 * HH))[t];
        sx += (b2f(x0.x) + b2f(x1.x)) + (b2f(x2.x) + b2f(x3.x));
        sy += (b2f(x0.y) + b2f(x1.y)) + (b2f(x2.y) + b2f(x3.y));
        sz += (b2f(x0.z) + b2f(x1.z)) + (b2f(x2.z) + b2f(x3.z));
        sw += (b2f(x0.w) + b2f(x1.w)) + (b2f(x2.w) + b2f(x3.w));
    }
    for (; i < e1; ++i) {
        ushort4 x = ((const ushort4*)(hsrc + (size_t)sorted[i] * HH))[t];
        sx += b2f(x.x); sy += b2f(x.y); sz += b2f(x.z); sw += b2f(x.w);
    }
    ushort4 o;
    o.x = f2bf(ep * b2f(ow.x) + sx);
    o.y = f2bf(ep * b2f(ow.y) + sy);
    o.z = f2bf(ep * b2f(ow.z) + sz);
    o.w = f2bf(ep * b2f(ow.w) + sw);
    ((ushort4*)(outb + (size_t)d * HH))[t] = o;
}

__global__ __launch_bounds__(256) void k_final(const float* __restrict__ part, int nslot,
                                               const float* __restrict__ bp0, const float* __restrict__ bpR,
                                               float* __restrict__ out) {
    __shared__ float s0[256], s1[256];
    int t = threadIdx.x;
    float a0 = 0.f, a1 = 0.f;
    for (int i = t; i < nslot; i += 256) { a0 += part[2 * i]; a1 += part[2 * i + 1]; }
    s0[t] = a0; s1[t] = a1;
    __syncthreads();
    for (int s = 128; s > 0; s >>= 1) {
        if (t < s) { s0[t] += s0[t + s]; s1[t] += s1[t + s]; }
        __syncthreads();
    }
    if (t == 0) {
        out[0] = s0[0] + bp0[0] + bpR[0] + bpR[2] + bpR[4] + bpR[6];
        out[1] = s1[0] + bp0[1] + bpR[1] + bpR[3] + bpR[5] + bpR[7];
    }
}

extern "C" void kernel_launch(void* const* d_in, const int* in_sizes, int n_in,
                              void* d_out, int out_size, void* d_ws, size_t ws_size,
                              hipStream_t stream)
{
    const float* feat = (const float*)d_in[0];
    const int*   esrc = (const int*)d_in[1];
    const int*   edst = (const int*)d_in[2];
    const float* eps0 = (const float*)d_in[3];
    const float* W0a  = (const float*)d_in[4];
    const float* b0a  = (const float*)d_in[5];
    const float* W0b  = (const float*)d_in[6];
    const float* b0b  = (const float*)d_in[7];
    const float* bn0a_g = (const float*)d_in[8];
    const float* bn0a_b = (const float*)d_in[9];
    const float* bn0a_m = (const float*)d_in[10];
    const float* bn0a_v = (const float*)d_in[11];
    const float* bnA0_g = (const float*)d_in[12];
    const float* bnA0_b = (const float*)d_in[13];
    const float* bnA0_m = (const float*)d_in[14];
    const float* bnA0_v = (const float*)d_in[15];
    const float* bnO0_g = (const float*)d_in[16];
    const float* bnO0_b = (const float*)d_in[17];
    const float* bnO0_m = (const float*)d_in[18];
    const float* bnO0_v = (const float*)d_in[19];
    const float* epsR = (const float*)d_in[20];
    const float* WRa  = (const float*)d_in[21];
    const float* bRa  = (const float*)d_in[22];
    const float* WRb  = (const float*)d_in[23];
    const float* bRb  = (const float*)d_in[24];
    const float* bnRa_g = (const float*)d_in[25];
    const float* bnRa_b = (const float*)d_in[26];
    const float* bnRa_m = (const float*)d_in[27];
    const float* bnRa_v = (const float*)d_in[28];
    const float* bnAR_g = (const float*)d_in[29];
    const float* bnAR_b = (const float*)d_in[30];
    const float* bnAR_m = (const float*)d_in[31];
    const float* bnAR_v = (const float*)d_in[32];
    const float* bnOR_g = (const float*)d_in[33];
    const float* bnOR_b = (const float*)d_in[34];
    const float* bnOR_m = (const float*)d_in[35];
    const float* bnOR_v = (const float*)d_in[36];
    const float* Wp0 = (const float*)d_in[37];
    const float* bp0 = (const float*)d_in[38];
    const float* WpR = (const float*)d_in[39];
    const float* bpR = (const float*)d_in[40];
    float* out = (float*)d_out;

    char* ws = (char*)d_ws;
    const size_t MB = 1024 * 1024;
    int*   starts = (int*)(ws + 0x10000);     // [0x10000, 0x14004)
    int*   cursor = (int*)(ws + 0x20000);     // [0x20000, 0x24000)
    int*   sorted = (int*)(ws + 0x30000);     // [0x30000, 0x70000) 256 KiB
    float* part   = (float*)(ws + 0x70000);   // 6144*2 f32 (48 KiB)
    unsigned short* featb = (unsigned short*)(ws + 1 * MB);    // [4096][4096] bf16, 32 MiB
    unsigned short* w0at  = (unsigned short*)(ws + 33 * MB);   // [512][4096] bf16, 4 MiB
    unsigned short* wt    = (unsigned short*)(ws + 37 * MB);   // 7 x [512][512] bf16
    unsigned short* G0b   = (unsigned short*)(ws + 41 * MB);   // [4096][512] bf16
    unsigned short* xb = (unsigned short*)(ws + 49 * MB);      // [4096][512] bf16
    unsigned short* yb = (unsigned short*)(ws + 53 * MB);      // [4096][512] bf16
    unsigned short* hb = (unsigned short*)(ws + 57 * MB);      // 4 x [4096][512] bf16

    // ---- edge sort (histscan zeroes cursor; no memset dispatch) ----
    k_histscan<<<1, 1024, 0, stream>>>(edst, starts, cursor);
    k_scatter<<<EE / 256, 256, 0, stream>>>(esrc, edst, starts, cursor, sorted);
    k_binsort<<<NN / 256, 256, 0, stream>>>(starts, sorted);

    // ---- prep: cvt feat + feat.Wp0 dot (blocks 0..4095) + 3840 weight-transpose tiles ----
    k_prep<<<4096 + 3840, 256, 0, stream>>>(feat, Wp0, featb, part,
                                            W0a, W0b, WRa, WRb, w0at, wt);

    const dim3 gg(NN / 64, HH / 64);   // 512 blocks, 2 per CU

    // ---- layer 0 (reassociated: G0 = feat@W0a first, then aggregate) ----
    k_gemmT<0, false><<<gg, 256, 0, stream>>>(featb, w0at, NN,
        nullptr, nullptr, nullptr, nullptr, nullptr, nullptr, nullptr, nullptr, nullptr,
        G0b, nullptr, nullptr, 0);
    k_agg0<<<NN, 128, 0, stream>>>(G0b, starts, sorted, eps0, b0a,
                                   bn0a_g, bn0a_b, bn0a_m, bn0a_v, xb);
    k_gemmT<3, true><<<gg, 256, 0, stream>>>(xb, wt, HH,
        b0b, bnA0_g, bnA0_b, bnA0_m, bnA0_v, bnO0_g, bnO0_b, bnO0_m, bnO0_v,
        hb, WpR, part, 4096);

    // ---- layers 1..3 ----
    for (int i = 0; i < 3; ++i) {
        const unsigned short* hp = hb + (size_t)i * NN * HH;
        unsigned short* hn = hb + (size_t)(i + 1) * NN * HH;
        k_aggL<<<NN, 128, 0, stream>>>(hp, starts, sorted, epsR + i, xb);
        k_gemmT<1, false><<<gg, 256, 0, stream>>>(xb, wt + (size_t)(1 + i) * HH * HH, HH,
            bRa + (size_t)i * HH,
            bnRa_g + (size_t)i * HH, bnRa_b + (size_t)i * HH, bnRa_m + (size_t)i * HH, bnRa_v + (size_t)i * HH,
            nullptr, nullptr, nullptr, nullptr,
            yb, nullptr, nullptr, 0);
        k_gemmT<3, true><<<gg, 256, 0, stream>>>(yb, wt + (size_t)(4 + i) * HH * HH, HH,
            bRb + (size_t)i * HH,
            bnAR_g + (size_t)i * HH, bnAR_b + (size_t)i * HH, bnAR_m + (size_t)i * HH, bnAR_v + (size_t)i * HH,
            bnOR_g + (size_t)i * HH, bnOR_b + (size_t)i * HH, bnOR_m + (size_t)i * HH, bnOR_v + (size_t)i * HH,
            hn, WpR + (size_t)(i + 1) * NN * HH * 2, part, 4096 + (i + 1) * 512);
    }

    // ---- jumping-knowledge readout final reduce ----
    k_final<<<1, 256, 0, stream>>>(part, 4096 + 4 * 512, bp0, bpR, out);
}

// Round 10
// 302.097 us; speedup vs baseline: 2.2525x; 1.0228x over previous
//
#include <hip/hip_runtime.h>
#include <cstdint>
#include <cstddef>

typedef __attribute__((ext_vector_type(8))) short short8;   // 8 bf16 (4 VGPRs)
typedef __attribute__((ext_vector_type(4))) float f32x4;    // 4 fp32 acc
typedef __attribute__((ext_vector_type(4))) float f4;
typedef __attribute__((ext_vector_type(2))) float f2;
typedef __attribute__((ext_vector_type(4))) unsigned short us4;

#define NN 4096
#define HH 512
#define EE 65536

// async global->LDS, 16B per lane (dest must be linear: base + lane*16)
#define GLOAD(gp, lp) __builtin_amdgcn_global_load_lds( \
    (const __attribute__((address_space(1))) void*)(gp), \
    (__attribute__((address_space(3))) void*)(lp), 16, 0, 0)

__device__ __forceinline__ unsigned short f2bf(float x) {
    union { float f; unsigned u; } un; un.f = x;
    unsigned r = un.u + 0x7fffu + ((un.u >> 16) & 1u);   // round-to-nearest-even
    return (unsigned short)(r >> 16);
}
__device__ __forceinline__ float b2f(unsigned short v) {
    union { unsigned u; float f; } un; un.u = ((unsigned)v) << 16; return un.f;
}

// ---------------- edge sort: fused hist+scan (1 block, also zeroes cursor) ----------------
__global__ __launch_bounds__(1024) void k_histscan(const int* __restrict__ edst,
                                                   int* __restrict__ starts,
                                                   int* __restrict__ cursor) {
    __shared__ int cnt[NN];
    __shared__ int wtot[16], woff[16];
    const int t = threadIdx.x;
    for (int i = t; i < NN; i += 1024) { cnt[i] = 0; cursor[i] = 0; }
    __syncthreads();
    for (int i = t; i < EE; i += 1024) atomicAdd(&cnt[edst[i]], 1);
    __syncthreads();
    const int b = t * 4;
    const int c0 = cnt[b], c1 = cnt[b + 1], c2 = cnt[b + 2], c3 = cnt[b + 3];
    const int s = c0 + c1 + c2 + c3;
    const int lane = t & 63, wv = t >> 6;
    int inc = s;
    for (int d = 1; d < 64; d <<= 1) {
        int v = __shfl_up(inc, d);
        if (lane >= d) inc += v;
    }
    if (lane == 63) wtot[wv] = inc;
    __syncthreads();
    if (t == 0) {
        int a = 0;
        for (int i = 0; i < 16; ++i) { woff[i] = a; a += wtot[i]; }
        starts[NN] = a;
    }
    __syncthreads();
    int run = woff[wv] + inc - s;
    starts[b] = run; run += c0;
    starts[b + 1] = run; run += c1;
    starts[b + 2] = run; run += c2;
    starts[b + 3] = run;
}

__global__ void k_scatter(const int* __restrict__ src, const int* __restrict__ dst,
                          const int* __restrict__ starts, int* __restrict__ cursor,
                          int* __restrict__ sorted) {
    int e = blockIdx.x * 256 + threadIdx.x;
    if (e < EE) {
        int d = dst[e];
        int p = starts[d] + atomicAdd(&cursor[d], 1);
        sorted[p] = src[e];
    }
}

__global__ void k_binsort(const int* __restrict__ starts, int* __restrict__ a) {
    int d = blockIdx.x * 256 + threadIdx.x;
    if (d < NN) {
        int s = starts[d], e = starts[d + 1];
        for (int i = s + 1; i < e; ++i) {
            int v = a[i]; int j = i - 1;
            while (j >= s && a[j] > v) { a[j + 1] = a[j]; --j; }
            a[j + 1] = v;
        }
    }
}

// ---------------- prep: blocks 0..4095 = cvt+dot0 slice; 4096.. = weight transposes ----------------
__global__ __launch_bounds__(256) void k_prep(const float* __restrict__ feat,
                                              const float* __restrict__ Wp0,
                                              unsigned short* __restrict__ featb,
                                              float* __restrict__ part,
                                              const float* __restrict__ W0a,
                                              const float* __restrict__ W0b,
                                              const float* __restrict__ WRa,
                                              const float* __restrict__ WRb,
                                              unsigned short* __restrict__ w0at,
                                              unsigned short* __restrict__ wt) {
    __shared__ f4 fs[1024];
    __shared__ float s0[256], s1[256];
    __shared__ float tile[32][33];
    const int t = threadIdx.x;
    const int bid = blockIdx.x;
    if (bid < 4096) {
        const long B0 = (long)bid * 1024;
        const f4* ff = (const f4*)feat;
        const f4* ww = (const f4*)Wp0;
        f4 v[4];
#pragma unroll
        for (int k = 0; k < 4; ++k)
            v[k] = __builtin_nontemporal_load(ff + B0 + k * 256 + t);
#pragma unroll
        for (int k = 0; k < 4; ++k) {
            fs[k * 256 + t] = v[k];
            us4 o;
            o.x = f2bf(v[k].x); o.y = f2bf(v[k].y); o.z = f2bf(v[k].z); o.w = f2bf(v[k].w);
            __builtin_nontemporal_store(o, (us4*)featb + B0 + k * 256 + t);
        }
        f4 wv[8];
#pragma unroll
        for (int k = 0; k < 8; ++k)
            wv[k] = __builtin_nontemporal_load(ww + 2 * B0 + k * 256 + t);
        __syncthreads();
        float a0 = 0.f, a1 = 0.f;
#pragma unroll
        for (int k = 0; k < 8; ++k) {
            const int q = k * 256 + t;
            f2 fp = *(const f2*)((const char*)fs + (size_t)q * 8);
            a0 += fp.x * wv[k].x + fp.y * wv[k].z;
            a1 += fp.x * wv[k].y + fp.y * wv[k].w;
        }
        s0[t] = a0; s1[t] = a1;
        __syncthreads();
        for (int s = 128; s > 0; s >>= 1) {
            if (t < s) { s0[t] += s0[t + s]; s1[t] += s1[t + s]; }
            __syncthreads();
        }
        if (t == 0) { part[2 * bid] = s0[0]; part[2 * bid + 1] = s1[0]; }
    } else {
        const int tix = bid - 4096;
        const float* W; unsigned short* Wt; int K, kb, nb;
        if (tix < 2048) {                 // W0a: 128 x 16 tiles of 32x32
            W = W0a; Wt = w0at; K = NN; kb = tix >> 4; nb = tix & 15;
        } else {
            const int t2 = tix - 2048;    // 7 x 256 tiles
            const int z = t2 >> 8, r = t2 & 255;
            W = (z == 0) ? W0b : (z < 4) ? WRa + (size_t)(z - 1) * HH * HH
                                         : WRb + (size_t)(z - 4) * HH * HH;
            Wt = wt + (size_t)z * HH * HH; K = HH; kb = r >> 4; nb = r & 15;
        }
        const int k0 = kb * 32, n0 = nb * 32;
        const int tx = t & 31, ty = t >> 5;
        for (int r = ty; r < 32; r += 8)
            tile[r][tx] = W[(size_t)(k0 + r) * HH + n0 + tx];
        __syncthreads();
        for (int r = ty; r < 32; r += 8)
            Wt[(size_t)(n0 + r) * K + k0 + tx] = f2bf(tile[tx][r]);
    }
}

// ---------------- gemm0: 128x128 tile, BK=64, 4 waves, split-K=4, XOR-swizzled LDS ----------------
// grid (32, 4, 4) = 512 blocks (2/CU). Per wave: 64x64 quadrant, acc 4x4 (1:2 ds:MFMA ratio).
__global__ __launch_bounds__(256) void k_gemm0(
    const unsigned short* __restrict__ A, const unsigned short* __restrict__ Bt,
    float* __restrict__ outf)
{
    constexpr int K = NN, N = HH;
    __shared__ alignas(16) unsigned short As[2 * 8192];   // 2 x 128x64 = 32 KiB
    __shared__ alignas(16) unsigned short Bs[2 * 8192];   // 32 KiB
    const int t = threadIdx.x;
    const int lane = t & 63, w = t >> 6;
    const int wr = w >> 1, wc = w & 1;
    const int l15 = lane & 15, l4 = lane >> 4;
    const int m0 = blockIdx.x * 128, n0 = blockIdx.y * 128;
    const int kbase = blockIdx.z * (K / 4);

    f32x4 acc[4][4];
#pragma unroll
    for (int i = 0; i < 4; ++i)
#pragma unroll
        for (int j = 0; j < 4; ++j) acc[i][j] = (f32x4){0.f, 0.f, 0.f, 0.f};

    // tile 128 rows x 8 chunks(16B) = 1024 chunks; thread t -> chunks {t, t+256, t+512, t+768}
    // -> rows ar+{0,32,64,96}, same col; source col XOR-swizzled by row&7 (invariant across +32).
    const int ar = t >> 3;
    const int ac = (t & 7) ^ (ar & 7);
    const unsigned short* ga = A + (size_t)(m0 + ar) * K + kbase + ac * 8;
    const unsigned short* gb = Bt + (size_t)(n0 + ar) * K + kbase + ac * 8;

    auto stage = [&](int kt, int buf) {
        const int ko = kt * 64;
        unsigned short* Ad = As + buf * 8192 + t * 8;
        unsigned short* Bd = Bs + buf * 8192 + t * 8;
        GLOAD(ga + ko, Ad);
        GLOAD(ga + (size_t)32 * K + ko, Ad + 2048);
        GLOAD(ga + (size_t)64 * K + ko, Ad + 4096);
        GLOAD(ga + (size_t)96 * K + ko, Ad + 6144);
        GLOAD(gb + ko, Bd);
        GLOAD(gb + (size_t)32 * K + ko, Bd + 2048);
        GLOAD(gb + (size_t)64 * K + ko, Bd + 4096);
        GLOAD(gb + (size_t)96 * K + ko, Bd + 6144);
    };

    const int rsw = l15 & 7;
    const int nk = (K / 4) >> 6;          // 16
    stage(0, 0);
    __syncthreads();
    for (int kt = 0; kt < nk; ++kt) {
        const int cur = kt & 1;
        if (kt + 1 < nk) stage(kt + 1, cur ^ 1);
        const unsigned short* Ac = As + cur * 8192;
        const unsigned short* Bc = Bs + cur * 8192;
        short8 aF[4][2], bF[4][2];
#pragma unroll
        for (int i = 0; i < 4; ++i)
#pragma unroll
            for (int ks = 0; ks < 2; ++ks)
                aF[i][ks] = *(const short8*)(Ac + (wr * 64 + i * 16 + l15) * 64
                                                + (((ks * 4 + l4) ^ rsw) * 8));
#pragma unroll
        for (int j = 0; j < 4; ++j)
#pragma unroll
            for (int ks = 0; ks < 2; ++ks)
                bF[j][ks] = *(const short8*)(Bc + (wc * 64 + j * 16 + l15) * 64
                                                + (((ks * 4 + l4) ^ rsw) * 8));
#pragma unroll
        for (int ks = 0; ks < 2; ++ks)
#pragma unroll
            for (int i = 0; i < 4; ++i)
#pragma unroll
                for (int j = 0; j < 4; ++j)
                    acc[i][j] = __builtin_amdgcn_mfma_f32_16x16x32_bf16(aF[i][ks], bF[j][ks], acc[i][j], 0, 0, 0);
        __syncthreads();
    }

    float* op = outf + (size_t)blockIdx.z * NN * N;
    const int mrow = m0 + wr * 64;
#pragma unroll
    for (int j = 0; j < 4; ++j) {
        const int cg = n0 + wc * 64 + j * 16 + l15;
#pragma unroll
        for (int i = 0; i < 4; ++i)
#pragma unroll
            for (int r = 0; r < 4; ++r)
                op[(size_t)(mrow + i * 16 + l4 * 4 + r) * N + cg] = acc[i][j][r];
    }
}

// sum 4 split-K partials -> bf16 G0b
__global__ __launch_bounds__(256) void k_red4b(const float* __restrict__ p,
                                               unsigned short* __restrict__ G0b) {
    const long S = (long)NN * HH / 4;
    long i = blockIdx.x * 256L + threadIdx.x;
    float4 a = ((const float4*)p)[i];
    float4 b = ((const float4*)p)[i + S];
    float4 c = ((const float4*)p)[i + 2 * S];
    float4 d = ((const float4*)p)[i + 3 * S];
    us4 o;
    o.x = f2bf((a.x + b.x) + (c.x + d.x));
    o.y = f2bf((a.y + b.y) + (c.y + d.y));
    o.z = f2bf((a.z + b.z) + (c.z + d.z));
    o.w = f2bf((a.w + b.w) + (c.w + d.w));
    ((us4*)G0b)[i] = o;
}

// ---------------- H-GEMM: 128x64 tile, BK=64, 4 waves (each 64x32, acc 4x2), swizzled ----------------
// grid (32, 8) = 256 blocks. EPI 1: +bias,BN,ReLU -> bf16. EPI 3: +bias,BN,ReLU,BN,ReLU -> bf16 (+DOT).
template<int EPI, bool DOT>
__global__ __launch_bounds__(256) void k_gemmH(
    const unsigned short* __restrict__ A, const unsigned short* __restrict__ Bt,
    const float* __restrict__ bias,
    const float* __restrict__ g1, const float* __restrict__ b1,
    const float* __restrict__ m1, const float* __restrict__ v1,
    const float* __restrict__ g2, const float* __restrict__ b2,
    const float* __restrict__ m2, const float* __restrict__ v2,
    unsigned short* __restrict__ outb,
    const float* __restrict__ wq, float* __restrict__ part, int slotbase)
{
    constexpr int K = HH, N = HH;
    __shared__ alignas(16) unsigned short As[2 * 8192];   // 2 x 128x64 = 32 KiB
    __shared__ alignas(16) unsigned short Bs[2 * 4096];   // 2 x 64x64 = 16 KiB
    const int t = threadIdx.x;
    const int lane = t & 63, w = t >> 6;
    const int wr = w >> 1, wc = w & 1;                    // wave = 64 rows x 32 cols
    const int l15 = lane & 15, l4 = lane >> 4;
    const int m0 = blockIdx.x * 128, n0 = blockIdx.y * 64;

    f32x4 acc[4][2];
#pragma unroll
    for (int i = 0; i < 4; ++i)
#pragma unroll
        for (int j = 0; j < 2; ++j) acc[i][j] = (f32x4){0.f, 0.f, 0.f, 0.f};

    const int ar = t >> 3;
    const int ac = (t & 7) ^ (ar & 7);
    const unsigned short* ga = A + (size_t)(m0 + ar) * K + ac * 8;
    const unsigned short* gb = Bt + (size_t)(n0 + ar) * K + ac * 8;

    auto stage = [&](int kt, int buf) {
        const int ko = kt * 64;
        unsigned short* Ad = As + buf * 8192 + t * 8;
        unsigned short* Bd = Bs + buf * 4096 + t * 8;
        GLOAD(ga + ko, Ad);
        GLOAD(ga + (size_t)32 * K + ko, Ad + 2048);
        GLOAD(ga + (size_t)64 * K + ko, Ad + 4096);
        GLOAD(ga + (size_t)96 * K + ko, Ad + 6144);
        GLOAD(gb + ko, Bd);
        GLOAD(gb + (size_t)32 * K + ko, Bd + 2048);
    };

    const int rsw = l15 & 7;
    const int nk = K >> 6;                // 8
    stage(0, 0);
    __syncthreads();
    for (int kt = 0; kt < nk; ++kt) {
        const int cur = kt & 1;
        if (kt + 1 < nk) stage(kt + 1, cur ^ 1);
        const unsigned short* Ac = As + cur * 8192;
        const unsigned short* Bc = Bs + cur * 4096;
        short8 aF[4][2], bF[2][2];
#pragma unroll
        for (int i = 0; i < 4; ++i)
#pragma unroll
            for (int ks = 0; ks < 2; ++ks)
                aF[i][ks] = *(const short8*)(Ac + (wr * 64 + i * 16 + l15) * 64
                                                + (((ks * 4 + l4) ^ rsw) * 8));
#pragma unroll
        for (int j = 0; j < 2; ++j)
#pragma unroll
            for (int ks = 0; ks < 2; ++ks)
                bF[j][ks] = *(const short8*)(Bc + (wc * 32 + j * 16 + l15) * 64
                                                + (((ks * 4 + l4) ^ rsw) * 8));
#pragma unroll
        for (int ks = 0; ks < 2; ++ks)
#pragma unroll
            for (int i = 0; i < 4; ++i)
#pragma unroll
                for (int j = 0; j < 2; ++j)
                    acc[i][j] = __builtin_amdgcn_mfma_f32_16x16x32_bf16(aF[i][ks], bF[j][ks], acc[i][j], 0, 0, 0);
        __syncthreads();
    }

    const int mrow = m0 + wr * 64;
    float d0 = 0.f, d1 = 0.f;
#pragma unroll
    for (int j = 0; j < 2; ++j) {
        const int cg = n0 + wc * 32 + j * 16 + l15;
        const float bi = bias[cg];
        const float sc1 = rsqrtf(v1[cg] + 1e-5f) * g1[cg];
        const float sh1 = b1[cg] - m1[cg] * sc1;
        float sc2 = 1.f, sh2 = 0.f;
        if (EPI == 3) {
            sc2 = rsqrtf(v2[cg] + 1e-5f) * g2[cg];
            sh2 = b2[cg] - m2[cg] * sc2;
        }
#pragma unroll
        for (int i = 0; i < 4; ++i) {
#pragma unroll
            for (int r = 0; r < 4; ++r) {
                const int rg = mrow + i * 16 + l4 * 4 + r;
                float x = acc[i][j][r];
                x = fmaxf((x + bi) * sc1 + sh1, 0.f);
                if (EPI == 3) x = fmaxf(x * sc2 + sh2, 0.f);
                outb[(size_t)rg * N + cg] = f2bf(x);
                if constexpr (DOT) {
                    f2 wvv = __builtin_nontemporal_load((const f2*)wq + (size_t)rg * N + cg);
                    d0 += x * wvv.x; d1 += x * wvv.y;
                }
            }
        }
    }
    if constexpr (DOT) {
        float* r0 = (float*)As;
        float* r1 = r0 + 256;
        __syncthreads();
        r0[t] = d0; r1[t] = d1;
        __syncthreads();
        for (int s = 128; s > 0; s >>= 1) {
            if (t < s) { r0[t] += r0[t + s]; r1[t] += r1[t + s]; }
            __syncthreads();
        }
        if (t == 0) {
            const int slot = slotbase + blockIdx.y * gridDim.x + blockIdx.x;
            part[2 * slot] = r0[0]; part[2 * slot + 1] = r1[0];
        }
    }
}

// ---------------- edge aggregation (gather-sum over sorted in-edges, 4x prefetch) ----------------
__global__ __launch_bounds__(128) void k_agg0(
    const unsigned short* __restrict__ G0, const int* __restrict__ starts,
    const int* __restrict__ sorted, const float* __restrict__ epsp,
    const float* __restrict__ bias,
    const float* __restrict__ bg, const float* __restrict__ bb,
    const float* __restrict__ bm, const float* __restrict__ bv,
    unsigned short* __restrict__ outb)
{
    const int d = blockIdx.x, t = threadIdx.x;
    const float ep = 1.0f + epsp[0];
    ushort4 ow = ((const ushort4*)(G0 + (size_t)d * HH))[t];
    float sx = 0.f, sy = 0.f, sz = 0.f, sw = 0.f;
    const int e0 = starts[d], e1 = starts[d + 1];
    int i = e0;
    for (; i + 4 <= e1; i += 4) {
        int q0 = sorted[i], q1 = sorted[i + 1], q2 = sorted[i + 2], q3 = sorted[i + 3];
        ushort4 x0 = ((const ushort4*)(G0 + (size_t)q0 * HH))[t];
        ushort4 x1 = ((const ushort4*)(G0 + (size_t)q1 * HH))[t];
        ushort4 x2 = ((const ushort4*)(G0 + (size_t)q2 * HH))[t];
        ushort4 x3 = ((const ushort4*)(G0 + (size_t)q3 * HH))[t];
        sx += (b2f(x0.x) + b2f(x1.x)) + (b2f(x2.x) + b2f(x3.x));
        sy += (b2f(x0.y) + b2f(x1.y)) + (b2f(x2.y) + b2f(x3.y));
        sz += (b2f(x0.z) + b2f(x1.z)) + (b2f(x2.z) + b2f(x3.z));
        sw += (b2f(x0.w) + b2f(x1.w)) + (b2f(x2.w) + b2f(x3.w));
    }
    for (; i < e1; ++i) {
        ushort4 x = ((const ushort4*)(G0 + (size_t)sorted[i] * HH))[t];
        sx += b2f(x.x); sy += b2f(x.y); sz += b2f(x.z); sw += b2f(x.w);
    }
    float4 bi = ((const float4*)bias)[t];
    float4 g4 = ((const float4*)bg)[t];
    float4 b4 = ((const float4*)bb)[t];
    float4 m4 = ((const float4*)bm)[t];
    float4 v4 = ((const float4*)bv)[t];
    float x0 = ep * b2f(ow.x) + sx + bi.x;
    float x1 = ep * b2f(ow.y) + sy + bi.y;
    float x2 = ep * b2f(ow.z) + sz + bi.z;
    float x3 = ep * b2f(ow.w) + sw + bi.w;
    x0 = fmaxf((x0 - m4.x) * rsqrtf(v4.x + 1e-5f) * g4.x + b4.x, 0.f);
    x1 = fmaxf((x1 - m4.y) * rsqrtf(v4.y + 1e-5f) * g4.y + b4.y, 0.f);
    x2 = fmaxf((x2 - m4.z) * rsqrtf(v4.z + 1e-5f) * g4.z + b4.z, 0.f);
    x3 = fmaxf((x3 - m4.w) * rsqrtf(v4.w + 1e-5f) * g4.w + b4.w, 0.f);
    ushort4 o; o.x = f2bf(x0); o.y = f2bf(x1); o.z = f2bf(x2); o.w = f2bf(x3);
    ((ushort4*)(outb + (size_t)d * HH))[t] = o;
}

__global__ __launch_bounds__(128) void k_aggL(
    const unsigned short* __restrict__ hsrc, const int* __restrict__ starts,
    const int* __restrict__ sorted, const float* __restrict__ epsp,
    unsigned short* __restrict__ outb)
{
    const int d = blockIdx.x, t = threadIdx.x;
    const float ep = 1.0f + epsp[0];
    ushort4 ow = ((const ushort4*)(hsrc + (size_t)d * HH))[t];
    float sx = 0.f, sy = 0.f, sz = 0.f, sw = 0.f;
    const int e0 = starts[d], e1 = starts[d + 1];
    int i = e0;
    for (; i + 4 <= e1; i += 4) {
        int q0 = sorted[i], q1 = sorted[i + 1], q2 = sorted[i + 2], q3 = sorted[i + 3];
        ushort4 x0 = ((const ushort4*)(hsrc + (size_t)q0 * HH))[t];
        ushort4 x1 = ((const ushort4*)(hsrc + (size_t)q1 * HH))[t];
        ushort4 x2 = ((const ushort4*)(hsrc + (size_t)q2 * HH))[t];
        ushort4 x3 = ((const ushort4*)(hsrc + (size_t)q3 * HH))[t];
        sx += (b2f(x0.x) + b2f(x1.x)) + (b2f(x2.x) + b2f(x3.x));
        sy += (b2f(x0.y) + b2f(x1.y)) + (b2f(x2.y) + b2f(x3.y));
        sz += (b2f(x0.z) + b2f(x1.z)) + (b2f(x2.z) + b2f(x3.z));
        sw += (b2f(x0.w) + b2f(x1.w)) + (b2f(x2.w) + b2f(x3.w));
    }
    for (; i < e1; ++i) {
        ushort4 x = ((const ushort4*)(hsrc + (size_t)sorted[i] * HH))[t];
        sx += b2f(x.x); sy += b2f(x.y); sz += b2f(x.z); sw += b2f(x.w);
    }
    ushort4 o;
    o.x = f2bf(ep * b2f(ow.x) + sx);
    o.y = f2bf(ep * b2f(ow.y) + sy);
    o.z = f2bf(ep * b2f(ow.z) + sz);
    o.w = f2bf(ep * b2f(ow.w) + sw);
    ((ushort4*)(outb + (size_t)d * HH))[t] = o;
}

__global__ __launch_bounds__(256) void k_final(const float* __restrict__ part, int nslot,
                                               const float* __restrict__ bp0, const float* __restrict__ bpR,
                                               float* __restrict__ out) {
    __shared__ float s0[256], s1[256];
    int t = threadIdx.x;
    float a0 = 0.f, a1 = 0.f;
    for (int i = t; i < nslot; i += 256) { a0 += part[2 * i]; a1 += part[2 * i + 1]; }
    s0[t] = a0; s1[t] = a1;
    __syncthreads();
    for (int s = 128; s > 0; s >>= 1) {
        if (t < s) { s0[t] += s0[t + s]; s1[t] += s1[t + s]; }
        __syncthreads();
    }
    if (t == 0) {
        out[0] = s0[0] + bp0[0] + bpR[0] + bpR[2] + bpR[4] + bpR[6];
        out[1] = s1[0] + bp0[1] + bpR[1] + bpR[3] + bpR[5] + bpR[7];
    }
}

extern "C" void kernel_launch(void* const* d_in, const int* in_sizes, int n_in,
                              void* d_out, int out_size, void* d_ws, size_t ws_size,
                              hipStream_t stream)
{
    const float* feat = (const float*)d_in[0];
    const int*   esrc = (const int*)d_in[1];
    const int*   edst = (const int*)d_in[2];
    const float* eps0 = (const float*)d_in[3];
    const float* W0a  = (const float*)d_in[4];
    const float* b0a  = (const float*)d_in[5];
    const float* W0b  = (const float*)d_in[6];
    const float* b0b  = (const float*)d_in[7];
    const float* bn0a_g = (const float*)d_in[8];
    const float* bn0a_b = (const float*)d_in[9];
    const float* bn0a_m = (const float*)d_in[10];
    const float* bn0a_v = (const float*)d_in[11];
    const float* bnA0_g = (const float*)d_in[12];
    const float* bnA0_b = (const float*)d_in[13];
    const float* bnA0_m = (const float*)d_in[14];
    const float* bnA0_v = (const float*)d_in[15];
    const float* bnO0_g = (const float*)d_in[16];
    const float* bnO0_b = (const float*)d_in[17];
    const float* bnO0_m = (const float*)d_in[18];
    const float* bnO0_v = (const float*)d_in[19];
    const float* epsR = (const float*)d_in[20];
    const float* WRa  = (const float*)d_in[21];
    const float* bRa  = (const float*)d_in[22];
    const float* WRb  = (const float*)d_in[23];
    const float* bRb  = (const float*)d_in[24];
    const float* bnRa_g = (const float*)d_in[25];
    const float* bnRa_b = (const float*)d_in[26];
    const float* bnRa_m = (const float*)d_in[27];
    const float* bnRa_v = (const float*)d_in[28];
    const float* bnAR_g = (const float*)d_in[29];
    const float* bnAR_b = (const float*)d_in[30];
    const float* bnAR_m = (const float*)d_in[31];
    const float* bnAR_v = (const float*)d_in[32];
    const float* bnOR_g = (const float*)d_in[33];
    const float* bnOR_b = (const float*)d_in[34];
    const float* bnOR_m = (const float*)d_in[35];
    const float* bnOR_v = (const float*)d_in[36];
    const float* Wp0 = (const float*)d_in[37];
    const float* bp0 = (const float*)d_in[38];
    const float* WpR = (const float*)d_in[39];
    const float* bpR = (const float*)d_in[40];
    float* out = (float*)d_out;

    char* ws = (char*)d_ws;
    const size_t MB = 1024 * 1024;
    int*   starts = (int*)(ws + 0x10000);     // [0x10000, 0x14004)
    int*   cursor = (int*)(ws + 0x20000);     // [0x20000, 0x24000)
    int*   sorted = (int*)(ws + 0x30000);     // [0x30000, 0x70000) 256 KiB
    float* part   = (float*)(ws + 0x70000);   // 6144*2 f32 (48 KiB)
    unsigned short* featb = (unsigned short*)(ws + 1 * MB);    // [4096][4096] bf16, 32 MiB
    unsigned short* w0at  = (unsigned short*)(ws + 33 * MB);   // [512][4096] bf16, 4 MiB
    unsigned short* wt    = (unsigned short*)(ws + 37 * MB);   // 7 x [512][512] bf16
    unsigned short* G0b   = (unsigned short*)(ws + 41 * MB);   // [4096][512] bf16
    unsigned short* xb = (unsigned short*)(ws + 49 * MB);      // [4096][512] bf16
    unsigned short* yb = (unsigned short*)(ws + 53 * MB);      // [4096][512] bf16
    unsigned short* hb = (unsigned short*)(ws + 57 * MB);      // 4 x [4096][512] bf16 (16 MiB)
    float* pbuf = (float*)(ws + 57 * MB);                      // 32 MiB split-K partials,
                                                               // dead before first hb write

    // ---- edge sort (histscan zeroes cursor; no memset dispatch) ----
    k_histscan<<<1, 1024, 0, stream>>>(edst, starts, cursor);
    k_scatter<<<EE / 256, 256, 0, stream>>>(esrc, edst, starts, cursor, sorted);
    k_binsort<<<NN / 256, 256, 0, stream>>>(starts, sorted);

    // ---- prep: cvt feat + feat.Wp0 dot (blocks 0..4095) + 3840 weight-transpose tiles ----
    k_prep<<<4096 + 3840, 256, 0, stream>>>(feat, Wp0, featb, part,
                                            W0a, W0b, WRa, WRb, w0at, wt);

    // ---- layer 0 (reassociated: G0 = feat@W0a first, then aggregate) ----
    k_gemm0<<<dim3(32, 4, 4), 256, 0, stream>>>(featb, w0at, pbuf);
    k_red4b<<<2048, 256, 0, stream>>>(pbuf, G0b);
    k_agg0<<<NN, 128, 0, stream>>>(G0b, starts, sorted, eps0, b0a,
                                   bn0a_g, bn0a_b, bn0a_m, bn0a_v, xb);

    const dim3 hg(32, 8);   // 256 blocks
    k_gemmH<3, true><<<hg, 256, 0, stream>>>(xb, wt,
        b0b, bnA0_g, bnA0_b, bnA0_m, bnA0_v, bnO0_g, bnO0_b, bnO0_m, bnO0_v,
        hb, WpR, part, 4096);

    // ---- layers 1..3 ----
    for (int i = 0; i < 3; ++i) {
        const unsigned short* hp = hb + (size_t)i * NN * HH;
        unsigned short* hn = hb + (size_t)(i + 1) * NN * HH;
        k_aggL<<<NN, 128, 0, stream>>>(hp, starts, sorted, epsR + i, xb);
        k_gemmH<1, false><<<hg, 256, 0, stream>>>(xb, wt + (size_t)(1 + i) * HH * HH,
            bRa + (size_t)i * HH,
            bnRa_g + (size_t)i * HH, bnRa_b + (size_t)i * HH, bnRa_m + (size_t)i * HH, bnRa_v + (size_t)i * HH,
            nullptr, nullptr, nullptr, nullptr,
            yb, nullptr, nullptr, 0);
        k_gemmH<3, true><<<hg, 256, 0, stream>>>(yb, wt + (size_t)(4 + i) * HH * HH,
            bRb + (size_t)i * HH,
            bnAR_g + (size_t)i * HH, bnAR_b + (size_t)i * HH, bnAR_m + (size_t)i * HH, bnAR_v + (size_t)i * HH,
            bnOR_g + (size_t)i * HH, bnOR_b + (size_t)i * HH, bnOR_m + (size_t)i * HH, bnOR_v + (size_t)i * HH,
            hn, WpR + (size_t)(i + 1) * NN * HH * 2, part, 4096 + (i + 1) * 256);
    }

    // ---- jumping-knowledge readout final reduce ----
    k_final<<<1, 256, 0, stream>>>(part, 4096 + 4 * 256, bp0, bpR, out);
}